// Round 6
// baseline (283.146 us; speedup 1.0000x reference)
//
#include <hip/hip_runtime.h>
#include <hip/hip_fp16.h>
#include <math.h>

#define NN 50000
#define EE 800000
#define ET (EE + NN)
#define FIN 256
#define CCOUT 128
#define HH 2
#define HC 256
#define NEG 0.2f

#define NB_EDGE ((ET + 255) / 256)      // 3321
#define NB_EDGE4 ((ET + 1023) / 1024)   // 831 (count: 4 edges/thread)
#define NB_SCAN ((NN + 255) / 256)
#define NB_XPREP (NN / 4)

// prep grid: 1 detect + 2 watt + 64 W-conv + 32 linw-conv
#define PREP_W_BLOCKS 64
#define PREP_LW_BLOCKS 32
#define PREP_GRID (3 + PREP_W_BLOCKS + PREP_LW_BLOCKS)

// fused scatter+gemm1 interleave: groups of 5 blocks = 4 scatter + 1 gemm
#define G1X 391                          // (NN+127)/128
#define G1Y 2                            // HC/128
#define NB_G1 (G1X * G1Y)                // 782
#define FUSE_HEAD (NB_G1 * 5)            // 3910
#define SCAT_IN_HEAD (NB_G1 * 4)         // 3128
#define NB_FUSE (NB_EDGE + NB_G1)        // 4103

typedef __attribute__((ext_vector_type(8))) short short8;
typedef __attribute__((ext_vector_type(4))) float floatx4;
typedef _Float16 half2v __attribute__((ext_vector_type(2)));

// ---------------- helpers ----------------
__device__ __forceinline__ unsigned short f2bf(float f)
{
    union { float f; unsigned int u; } x; x.f = f;
    unsigned int r = x.u + 0x7fffu + ((x.u >> 16) & 1u);   // RNE
    return (unsigned short)(r >> 16);
}
__device__ __forceinline__ unsigned short f2h(float f)
{
    __half h = __float2half_rn(f);
    return *(const unsigned short*)&h;
}
__device__ __forceinline__ unsigned int permb(unsigned int a, unsigned int b, unsigned int s)
{
    return __builtin_amdgcn_perm(a, b, s);
}
__device__ __forceinline__ float fdot2u(unsigned int a, unsigned int b, float c)
{
    union { unsigned int u; half2v h; } x, y;
    x.u = a; y.u = b;
    return __builtin_amdgcn_fdot2(x.h, y.h, c, false);
}

__device__ __forceinline__ int load_idx(const int* ei32, int is64, int pos)
{
    return is64 ? ei32[2 * pos] : ei32[pos];
}

// ---------------- fused prep: detect + watt + weight bf16 conversion ----------------
__global__ __launch_bounds__(256) void prep_kernel(const float* __restrict__ W,
                                                   const float* __restrict__ att_s,
                                                   const float* __restrict__ att_d,
                                                   const float* __restrict__ lin_w,
                                                   const int* __restrict__ ei32,
                                                   float* __restrict__ was,
                                                   float* __restrict__ wad,
                                                   unsigned short* __restrict__ Wb,
                                                   unsigned short* __restrict__ linwb,
                                                   int* __restrict__ flag)
{
    int b = blockIdx.x, t = threadIdx.x;
    if (b == 0) {
        if (t < 64) {
            int v = ei32[2 * t + 1];
            unsigned long long m = __ballot(v != 0);
            if (t == 0) *flag = (m == 0ull) ? 1 : 0;
        }
    } else if (b <= 2) {
        int hd = b - 1;
        float as = 0.f, ad = 0.f;
        for (int c = 0; c < CCOUT; c++) {
            float wv = W[(size_t)(hd * CCOUT + c) * FIN + t];
            as += att_s[hd * CCOUT + c] * wv;
            ad += att_d[hd * CCOUT + c] * wv;
        }
        was[hd * FIN + t] = as;
        wad[hd * FIN + t] = ad;
    } else if (b < 3 + PREP_W_BLOCKS) {
        int i = (b - 3) * 256 + t;
        float4 v = *(const float4*)(W + (size_t)i * 4);
        ushort4 o;
        o.x = f2bf(v.x); o.y = f2bf(v.y); o.z = f2bf(v.z); o.w = f2bf(v.w);
        *(ushort4*)(Wb + (size_t)i * 4) = o;
    } else {
        int i = (b - 3 - PREP_W_BLOCKS) * 256 + t;
        float4 v = *(const float4*)(lin_w + (size_t)i * 4);
        ushort4 o;
        o.x = f2bf(v.x); o.y = f2bf(v.y); o.z = f2bf(v.z); o.w = f2bf(v.w);
        *(ushort4*)(linwb + (size_t)i * 4) = o;
    }
}

// ---------------- fused: count (fire-and-forget) || x->bf16 + fp32 attention logits ----
// R6 change: deg counting no longer uses the atomicAdd RETURN value (eord is
// gone -- the rank atomic moved into the scatter, where GEMM1 hides it).
// Fire-and-forget atomics retire without stalling the wave -> count half is
// throughput-bound, not latency-bound.
__global__ __launch_bounds__(256) void xprep_count_kernel(const float* __restrict__ x,
                                                          const float* __restrict__ was,
                                                          const float* __restrict__ wad,
                                                          unsigned short* __restrict__ xb,
                                                          float* __restrict__ a_s,
                                                          float* __restrict__ a_d,
                                                          const int* __restrict__ ei32,
                                                          const int* __restrict__ flag,
                                                          int* __restrict__ deg)
{
    int b = blockIdx.x, t = threadIdx.x;
    if (b < NB_EDGE4) {
        int base = b * 1024 + t;
        int is64 = *flag;
        int e0 = base, e1 = base + 256, e2 = base + 512, e3 = base + 768;
        int d0 = -1, d1 = -1, d2 = -1, d3 = -1;
        if (e0 < ET) d0 = (e0 < EE) ? load_idx(ei32, is64, EE + e0) : (e0 - EE);
        if (e1 < ET) d1 = (e1 < EE) ? load_idx(ei32, is64, EE + e1) : (e1 - EE);
        if (e2 < ET) d2 = (e2 < EE) ? load_idx(ei32, is64, EE + e2) : (e2 - EE);
        if (e3 < ET) d3 = (e3 < EE) ? load_idx(ei32, is64, EE + e3) : (e3 - EE);
        if (d0 >= 0) atomicAdd(&deg[d0], 1);
        if (d1 >= 0) atomicAdd(&deg[d1], 1);
        if (d2 >= 0) atomicAdd(&deg[d2], 1);
        if (d3 >= 0) atomicAdd(&deg[d3], 1);
    } else {
        int w = t >> 6, l = t & 63;
        int n = (b - NB_EDGE4) * 4 + w;
        float4 xv = *(const float4*)(x + (size_t)n * FIN + l * 4);
        ushort4 xs;
        xs.x = f2bf(xv.x); xs.y = f2bf(xv.y); xs.z = f2bf(xv.z); xs.w = f2bf(xv.w);
        *(ushort4*)(xb + (size_t)n * FIN + l * 4) = xs;

        float4 s0 = *(const float4*)(was + l * 4);
        float4 s1 = *(const float4*)(was + FIN + l * 4);
        float4 d0 = *(const float4*)(wad + l * 4);
        float4 d1 = *(const float4*)(wad + FIN + l * 4);
        float vs0 = xv.x * s0.x + xv.y * s0.y + xv.z * s0.z + xv.w * s0.w;
        float vs1 = xv.x * s1.x + xv.y * s1.y + xv.z * s1.z + xv.w * s1.w;
        float vd0 = xv.x * d0.x + xv.y * d0.y + xv.z * d0.z + xv.w * d0.w;
        float vd1 = xv.x * d1.x + xv.y * d1.y + xv.z * d1.z + xv.w * d1.w;
#pragma unroll
        for (int off = 32; off > 0; off >>= 1) {
            vs0 += __shfl_down(vs0, off);
            vs1 += __shfl_down(vs1, off);
            vd0 += __shfl_down(vd0, off);
            vd1 += __shfl_down(vd1, off);
        }
        if (l == 0) {
            a_s[n * 2 + 0] = vs0; a_s[n * 2 + 1] = vs1;
            a_d[n * 2 + 0] = vd0; a_d[n * 2 + 1] = vd1;
        }
    }
}

// ---------------- MFMA bf16 GEMM (standalone, used for GEMM2) ----------------
template <bool ADD_BIAS, bool OUT_BF16>
__global__ __launch_bounds__(256) void gemm_mfma(const unsigned short* __restrict__ A,
                                                 const unsigned short* __restrict__ B,
                                                 const float* __restrict__ bias,
                                                 void* __restrict__ Cout,
                                                 int M, int N, int K)
{
    const int LDT = 40;
    __shared__ unsigned short As[128 * LDT];
    __shared__ unsigned short Bs[128 * LDT];

    int tid = threadIdx.x;
    int wave = tid >> 6, lane = tid & 63;
    int wr = wave >> 1, wc = wave & 1;
    int quad = lane >> 4, l16 = lane & 15;
    int bm0 = blockIdx.x * 128;
    int bn0 = blockIdx.y * 128;

    floatx4 acc[4][4] = {};

    for (int kk = 0; kk < K; kk += 32) {
#pragma unroll
        for (int p = 0; p < 2; p++) {
            int idx = p * 256 + tid;
            int row = idx >> 2, seg = idx & 3;
            int grow = bm0 + row; if (grow >= M) grow = M - 1;
            uint4 va = *(const uint4*)(A + (size_t)grow * K + kk + seg * 8);
            *(uint4*)(&As[row * LDT + seg * 8]) = va;
            uint4 vb = *(const uint4*)(B + (size_t)(bn0 + row) * K + kk + seg * 8);
            *(uint4*)(&Bs[row * LDT + seg * 8]) = vb;
        }
        __syncthreads();

        short8 af[4], bfr[4];
#pragma unroll
        for (int mi = 0; mi < 4; mi++)
            af[mi] = *(const short8*)(&As[(wr * 64 + mi * 16 + l16) * LDT + quad * 8]);
#pragma unroll
        for (int ni = 0; ni < 4; ni++)
            bfr[ni] = *(const short8*)(&Bs[(wc * 64 + ni * 16 + l16) * LDT + quad * 8]);
#pragma unroll
        for (int mi = 0; mi < 4; mi++)
#pragma unroll
            for (int ni = 0; ni < 4; ni++)
                acc[mi][ni] = __builtin_amdgcn_mfma_f32_16x16x32_bf16(af[mi], bfr[ni], acc[mi][ni], 0, 0, 0);
        __syncthreads();
    }

#pragma unroll
    for (int mi = 0; mi < 4; mi++) {
#pragma unroll
        for (int ni = 0; ni < 4; ni++) {
            int col = bn0 + wc * 64 + ni * 16 + l16;
#pragma unroll
            for (int r = 0; r < 4; r++) {
                int row = bm0 + wr * 64 + mi * 16 + quad * 4 + r;
                if (row < M) {
                    float v = acc[mi][ni][r];
                    if (ADD_BIAS) v += bias[col];
                    if (OUT_BF16)
                        ((unsigned short*)Cout)[(size_t)row * N + col] = f2bf(v);
                    else
                        ((float*)Cout)[(size_t)row * N + col] = v;
                }
            }
        }
    }
}

// ---------------- FUSED: scatter (latency-bound) + GEMM1 (MFMA-bound), interleaved 4:1 ----
// R6: scatter allocates its rec slot via pos = atomicAdd(&cursor[d], 1)
// (cursor = copy of rowstart). The atomic-with-return round-trip hides under
// the co-resident GEMM1 MFMA blocks; slot order within a dest is arbitrary
// (aggregation is a commutative sum). eord buffer eliminated.
__global__ __launch_bounds__(256) void scatter_gemm1_kernel(
        const int* __restrict__ ei32, const int* __restrict__ flag,
        int* __restrict__ cursor,
        const float* __restrict__ a_s, const float* __restrict__ a_d,
        uint2* __restrict__ rec,
        const unsigned short* __restrict__ A,   // xb [NN, FIN]
        const unsigned short* __restrict__ B,   // Wb [HC, FIN]
        unsigned short* __restrict__ hb)        // out [NN, HC] fp16
{
    const int LDT = 40;
    __shared__ unsigned short As[128 * LDT];
    __shared__ unsigned short Bs[128 * LDT];

    int b = blockIdx.x, tid = threadIdx.x;
    int sb = -1, gb = -1;
    if (b < FUSE_HEAD) {
        int g = b / 5, r = b - g * 5;
        if (r < 4) sb = g * 4 + r; else gb = g;
    } else {
        sb = SCAT_IN_HEAD + (b - FUSE_HEAD);
    }

    if (sb >= 0) {
        int e = sb * 256 + tid;
        if (e < ET) {
            int is64 = *flag;
            int s, d;
            if (e < EE) { s = load_idx(ei32, is64, e); d = load_idx(ei32, is64, EE + e); }
            else { s = d = e - EE; }
            int pos = atomicAdd(&cursor[d], 1);      // issued early; overlaps a_s/a_d loads
            float e0 = a_s[s * 2 + 0] + a_d[d * 2 + 0];
            float e1 = a_s[s * 2 + 1] + a_d[d * 2 + 1];
            e0 = e0 > 0.f ? e0 : NEG * e0;
            e1 = e1 > 0.f ? e1 : NEG * e1;
            __half2 hp = __floats2half2_rn(__expf(e0), __expf(e1));
            uint2 r;
            r.x = (unsigned int)s;
            r.y = *(unsigned int*)&hp;
            rec[pos] = r;
        }
        return;
    }

    int bx = gb % G1X, by = gb / G1X;
    int wave = tid >> 6, lane = tid & 63;
    int wr = wave >> 1, wc = wave & 1;
    int quad = lane >> 4, l16 = lane & 15;
    int bm0 = bx * 128;
    int bn0 = by * 128;

    floatx4 acc[4][4] = {};

    for (int kk = 0; kk < FIN; kk += 32) {
#pragma unroll
        for (int p = 0; p < 2; p++) {
            int idx = p * 256 + tid;
            int row = idx >> 2, seg = idx & 3;
            int grow = bm0 + row; if (grow >= NN) grow = NN - 1;
            uint4 va = *(const uint4*)(A + (size_t)grow * FIN + kk + seg * 8);
            *(uint4*)(&As[row * LDT + seg * 8]) = va;
            uint4 vb = *(const uint4*)(B + (size_t)(bn0 + row) * FIN + kk + seg * 8);
            *(uint4*)(&Bs[row * LDT + seg * 8]) = vb;
        }
        __syncthreads();

        short8 af[4], bfr[4];
#pragma unroll
        for (int mi = 0; mi < 4; mi++)
            af[mi] = *(const short8*)(&As[(wr * 64 + mi * 16 + l16) * LDT + quad * 8]);
#pragma unroll
        for (int ni = 0; ni < 4; ni++)
            bfr[ni] = *(const short8*)(&Bs[(wc * 64 + ni * 16 + l16) * LDT + quad * 8]);
#pragma unroll
        for (int mi = 0; mi < 4; mi++)
#pragma unroll
            for (int ni = 0; ni < 4; ni++)
                acc[mi][ni] = __builtin_amdgcn_mfma_f32_16x16x32_bf16(af[mi], bfr[ni], acc[mi][ni], 0, 0, 0);
        __syncthreads();
    }

#pragma unroll
    for (int mi = 0; mi < 4; mi++) {
#pragma unroll
        for (int ni = 0; ni < 4; ni++) {
            int col = bn0 + wc * 64 + ni * 16 + l16;
#pragma unroll
            for (int r = 0; r < 4; r++) {
                int row = bm0 + wr * 64 + mi * 16 + quad * 4 + r;
                if (row < NN)
                    hb[(size_t)row * HC + col] = f2h(acc[mi][ni][r]);
            }
        }
    }
}

// ---------------- scan1: per-block inclusive scan + block totals ----------------
__global__ __launch_bounds__(256) void scan1(const int* __restrict__ deg,
                                             int* __restrict__ tmp, int* __restrict__ bsum)
{
    __shared__ int s[256];
    int i = blockIdx.x * 256 + threadIdx.x;
    int v = (i < NN) ? deg[i] : 0;
    s[threadIdx.x] = v;
    __syncthreads();
    for (int off = 1; off < 256; off <<= 1) {
        int add = (threadIdx.x >= off) ? s[threadIdx.x - off] : 0;
        __syncthreads();
        s[threadIdx.x] += add;
        __syncthreads();
    }
    if (i < NN) tmp[i] = s[threadIdx.x];
    if (threadIdx.x == 255) bsum[blockIdx.x] = s[255];
}

// ---------------- scan2+scan3 fused (also seeds the scatter cursor) ----------------
__global__ __launch_bounds__(256) void scan23(const int* __restrict__ deg,
                                              const int* __restrict__ tmp,
                                              const int* __restrict__ bsum,
                                              int* __restrict__ rowstart,
                                              int* __restrict__ cursor)
{
    __shared__ int s[256];
    int b = blockIdx.x, t = threadIdx.x;
    int v = (t < NB_SCAN && t < b) ? bsum[t] : 0;
    s[t] = v;
    __syncthreads();
#pragma unroll
    for (int off = 128; off > 0; off >>= 1) {
        if (t < off) s[t] += s[t + off];
        __syncthreads();
    }
    int offset = s[0];
    int i = b * 256 + t;
    if (i < NN) {
        int rs = tmp[i] - deg[i] + offset;
        rowstart[i] = rs;
        cursor[i] = rs;
    }
    if (i == 0) rowstart[NN] = ET;
}

// ---------------- gather-aggregate v11: agg7 structure + v_perm/v_dot2_f32_f16 ----
// wave per node, half-wave edge interleave, 4 gather chains in flight (8 edges/wave-iter).
// Channel math: pair two edges; v_perm packs (h_e0[c], h_e1[c]) as half2; one
// v_dot2_f32_f16 does both MACs. ~2x fewer VALU ops/edge than extract+FMA.
// Tail zero-fill uses perm selector 0x0C (constant 0x00) -- NOT 0x80, which is
// in the 0xFF-fill class and produced fp16 NaN (R3 failure).
// NOTE (R5 counters): this kernel is memory-path-bound (FETCH 187MB = analytic
// floor for dest-ordered random gathers across 8 XCDs; VALU cuts don't move it).
__global__ __launch_bounds__(256) void agg11_kernel(const unsigned short* __restrict__ hb,
                                                    const int* __restrict__ rowstart,
                                                    const uint2* __restrict__ rec,
                                                    const float* __restrict__ bias,
                                                    unsigned short* __restrict__ aggb)
{
    int wave = threadIdx.x >> 6, lane = threadIdx.x & 63;
    int d = blockIdx.x * 4 + wave;
    int half = lane >> 5;
    int l = lane & 31;
    int c = l * 8;
    // lanes 0-15: head0 (p = bytes 0-1 of rec.y), lanes 16-31: head1 (bytes 2-3)
    unsigned int selp  = (l & 16) ? 0x07060302u : 0x05040100u;
    unsigned int selps = (l & 16) ? 0x0C0C0302u : 0x0C0C0100u;   // (p, +0.0)
    const unsigned int ones = 0x3C003C00u;   // half2(1.0, 1.0)
    const unsigned long long* recq = (const unsigned long long*)rec;

    int j0 = rowstart[d], j1 = rowstart[d + 1];
    float a0 = 0.f, a1 = 0.f, a2 = 0.f, a3 = 0.f;
    float a4 = 0.f, a5 = 0.f, a6 = 0.f, a7 = 0.f;
    float psum = 0.f;

    int j = j0 + half;
    // 4 edges per half per iter (2 dot2-pairs), 4 gathers in flight
    for (; j + 6 < j1; j += 8) {
        unsigned long long q0 = recq[j], q1 = recq[j + 2], q2 = recq[j + 4], q3 = recq[j + 6];
        unsigned int pp01 = permb((unsigned int)(q1 >> 32), (unsigned int)(q0 >> 32), selp);
        unsigned int pp23 = permb((unsigned int)(q3 >> 32), (unsigned int)(q2 >> 32), selp);
        psum = fdot2u(pp01, ones, psum);
        psum = fdot2u(pp23, ones, psum);
        uint4 h0 = *(const uint4*)(hb + (size_t)(unsigned int)q0 * HC + c);
        uint4 h1 = *(const uint4*)(hb + (size_t)(unsigned int)q1 * HC + c);
        uint4 h2 = *(const uint4*)(hb + (size_t)(unsigned int)q2 * HC + c);
        uint4 h3 = *(const uint4*)(hb + (size_t)(unsigned int)q3 * HC + c);
        a0 = fdot2u(permb(h1.x, h0.x, 0x05040100u), pp01, a0);
        a0 = fdot2u(permb(h3.x, h2.x, 0x05040100u), pp23, a0);
        a1 = fdot2u(permb(h1.x, h0.x, 0x07060302u), pp01, a1);
        a1 = fdot2u(permb(h3.x, h2.x, 0x07060302u), pp23, a1);
        a2 = fdot2u(permb(h1.y, h0.y, 0x05040100u), pp01, a2);
        a2 = fdot2u(permb(h3.y, h2.y, 0x05040100u), pp23, a2);
        a3 = fdot2u(permb(h1.y, h0.y, 0x07060302u), pp01, a3);
        a3 = fdot2u(permb(h3.y, h2.y, 0x07060302u), pp23, a3);
        a4 = fdot2u(permb(h1.z, h0.z, 0x05040100u), pp01, a4);
        a4 = fdot2u(permb(h3.z, h2.z, 0x05040100u), pp23, a4);
        a5 = fdot2u(permb(h1.z, h0.z, 0x07060302u), pp01, a5);
        a5 = fdot2u(permb(h3.z, h2.z, 0x07060302u), pp23, a5);
        a6 = fdot2u(permb(h1.w, h0.w, 0x05040100u), pp01, a6);
        a6 = fdot2u(permb(h3.w, h2.w, 0x05040100u), pp23, a6);
        a7 = fdot2u(permb(h1.w, h0.w, 0x07060302u), pp01, a7);
        a7 = fdot2u(permb(h3.w, h2.w, 0x07060302u), pp23, a7);
    }
    // tail: one edge per half per iter, zero-padded pair (selector 0x0C = 0x00)
    for (; j < j1; j += 2) {
        unsigned long long q0 = recq[j];
        unsigned int pp = permb(0u, (unsigned int)(q0 >> 32), selps);
        psum = fdot2u(pp, ones, psum);
        uint4 h0 = *(const uint4*)(hb + (size_t)(unsigned int)q0 * HC + c);
        a0 = fdot2u(permb(0u, h0.x, 0x0C0C0100u), pp, a0);
        a1 = fdot2u(permb(0u, h0.x, 0x0C0C0302u), pp, a1);
        a2 = fdot2u(permb(0u, h0.y, 0x0C0C0100u), pp, a2);
        a3 = fdot2u(permb(0u, h0.y, 0x0C0C0302u), pp, a3);
        a4 = fdot2u(permb(0u, h0.z, 0x0C0C0100u), pp, a4);
        a5 = fdot2u(permb(0u, h0.z, 0x0C0C0302u), pp, a5);
        a6 = fdot2u(permb(0u, h0.w, 0x0C0C0100u), pp, a6);
        a7 = fdot2u(permb(0u, h0.w, 0x0C0C0302u), pp, a7);
    }

    a0 += __shfl_xor(a0, 32);
    a1 += __shfl_xor(a1, 32);
    a2 += __shfl_xor(a2, 32);
    a3 += __shfl_xor(a3, 32);
    a4 += __shfl_xor(a4, 32);
    a5 += __shfl_xor(a5, 32);
    a6 += __shfl_xor(a6, 32);
    a7 += __shfl_xor(a7, 32);
    psum += __shfl_xor(psum, 32);

    if (half == 0) {
        float inv = 1.f / fmaxf(psum, 1e-16f);
        float4 b0 = *(const float4*)(bias + c);
        float4 b1 = *(const float4*)(bias + c + 4);
        float v0 = a0 * inv + b0.x;
        float v1 = a1 * inv + b0.y;
        float v2 = a2 * inv + b0.z;
        float v3 = a3 * inv + b0.w;
        float v4 = a4 * inv + b1.x;
        float v5 = a5 * inv + b1.y;
        float v6 = a6 * inv + b1.z;
        float v7 = a7 * inv + b1.w;
        v0 = v0 > 0.f ? v0 : expm1f(v0);
        v1 = v1 > 0.f ? v1 : expm1f(v1);
        v2 = v2 > 0.f ? v2 : expm1f(v2);
        v3 = v3 > 0.f ? v3 : expm1f(v3);
        v4 = v4 > 0.f ? v4 : expm1f(v4);
        v5 = v5 > 0.f ? v5 : expm1f(v5);
        v6 = v6 > 0.f ? v6 : expm1f(v6);
        v7 = v7 > 0.f ? v7 : expm1f(v7);
        uint4 o;
        o.x = (unsigned int)f2bf(v0) | ((unsigned int)f2bf(v1) << 16);
        o.y = (unsigned int)f2bf(v2) | ((unsigned int)f2bf(v3) << 16);
        o.z = (unsigned int)f2bf(v4) | ((unsigned int)f2bf(v5) << 16);
        o.w = (unsigned int)f2bf(v6) | ((unsigned int)f2bf(v7) << 16);
        *(uint4*)(aggb + (size_t)d * HC + c) = o;
    }
}

// ---------------- launch ----------------
extern "C" void kernel_launch(void* const* d_in, const int* in_sizes, int n_in,
                              void* d_out, int out_size, void* d_ws, size_t ws_size,
                              hipStream_t stream)
{
    const float* x       = (const float*)d_in[0];
    const int*   ei32    = (const int*)d_in[1];
    const float* W       = (const float*)d_in[2];
    const float* att_src = (const float*)d_in[3];
    const float* att_dst = (const float*)d_in[4];
    const float* bias    = (const float*)d_in[5];
    const float* lin_w   = (const float*)d_in[6];
    const float* lin_b   = (const float*)d_in[7];
    float* out = (float*)d_out;

    char* ws = (char*)d_ws;
    size_t off = 0;
    auto alloc = [&](size_t bytes) -> void* {
        void* p = ws + off;
        off += (bytes + 255) & ~(size_t)255;
        return p;
    };

    // zero-init region first (deg only)
    int*   deg    = (int*)alloc((size_t)NN * 4);
    size_t zero_bytes = off;

    int*   flag     = (int*)alloc(256);
    int*   tmp      = (int*)alloc((size_t)NN * 4);
    int*   bsum     = (int*)alloc(1024);
    int*   rowstart = (int*)alloc((size_t)(NN + 1) * 4);
    int*   cursor   = (int*)alloc((size_t)NN * 4);
    float* was      = (float*)alloc((size_t)HH * FIN * 4);
    float* wad      = (float*)alloc((size_t)HH * FIN * 4);
    float* a_s      = (float*)alloc((size_t)NN * 2 * 4);
    float* a_d      = (float*)alloc((size_t)NN * 2 * 4);
    uint2* rec      = (uint2*)alloc((size_t)ET * 8);
    unsigned short* xb     = (unsigned short*)alloc((size_t)NN * FIN * 2);
    unsigned short* Wb     = (unsigned short*)alloc((size_t)HC * FIN * 2);
    unsigned short* linwb  = (unsigned short*)alloc((size_t)CCOUT * HC * 2);
    unsigned short* hb     = (unsigned short*)alloc((size_t)NN * HC * 2);   // fp16 [NN][HC]
    unsigned short* aggb   = (unsigned short*)alloc((size_t)NN * HC * 2);   // bf16 [NN][HC]

    hipMemsetAsync(d_ws, 0, zero_bytes, stream);

    prep_kernel<<<PREP_GRID, 256, 0, stream>>>(W, att_src, att_dst, lin_w, ei32,
                                               was, wad, Wb, linwb, flag);

    xprep_count_kernel<<<NB_XPREP + NB_EDGE4, 256, 0, stream>>>(x, was, wad, xb, a_s, a_d,
                                                                ei32, flag, deg);

    scan1<<<NB_SCAN, 256, 0, stream>>>(deg, tmp, bsum);
    scan23<<<NB_SCAN, 256, 0, stream>>>(deg, tmp, bsum, rowstart, cursor);

    scatter_gemm1_kernel<<<NB_FUSE, 256, 0, stream>>>(ei32, flag, cursor,
                                                      a_s, a_d, rec, xb, Wb, hb);

    agg11_kernel<<<NN / 4, 256, 0, stream>>>(hb, rowstart, rec, bias, aggb);

    dim3 g2((NN + 127) / 128, CCOUT / 128);
    gemm_mfma<true, false><<<g2, 256, 0, stream>>>(aggb, linwb, lin_b, out, NN, CCOUT, HC);
}

// Round 7
// 275.068 us; speedup vs baseline: 1.0294x; 1.0294x over previous
//
#include <hip/hip_runtime.h>
#include <hip/hip_fp16.h>
#include <math.h>

#define NN 50000
#define EE 800000
#define ET (EE + NN)
#define FIN 256
#define CCOUT 128
#define HH 2
#define HC 256
#define NEG 0.2f

#define NB_EDGE ((ET + 255) / 256)      // 3321
#define NB_EDGE8 ((ET + 2047) / 2048)   // 416 (count: 8 edges/thread, 8 chains in flight)
#define NB_SCAN ((NN + 255) / 256)
#define NB_XPREP (NN / 4)

// prep grid: 1 detect + 2 watt + 64 W-conv + 32 linw-conv
#define PREP_W_BLOCKS 64
#define PREP_LW_BLOCKS 32
#define PREP_GRID (3 + PREP_W_BLOCKS + PREP_LW_BLOCKS)

// fused scatter+gemm1 interleave: groups of 5 blocks = 4 scatter + 1 gemm
#define G1X 391                          // (NN+127)/128
#define G1Y 2                            // HC/128
#define NB_G1 (G1X * G1Y)                // 782
#define FUSE_HEAD (NB_G1 * 5)            // 3910
#define SCAT_IN_HEAD (NB_G1 * 4)        // 3128
#define NB_FUSE (NB_EDGE + NB_G1)        // 4103

typedef __attribute__((ext_vector_type(8))) short short8;
typedef __attribute__((ext_vector_type(4))) float floatx4;
typedef _Float16 half2v __attribute__((ext_vector_type(2)));

// ---------------- helpers ----------------
__device__ __forceinline__ unsigned short f2bf(float f)
{
    union { float f; unsigned int u; } x; x.f = f;
    unsigned int r = x.u + 0x7fffu + ((x.u >> 16) & 1u);   // RNE
    return (unsigned short)(r >> 16);
}
__device__ __forceinline__ unsigned short f2h(float f)
{
    __half h = __float2half_rn(f);
    return *(const unsigned short*)&h;
}
__device__ __forceinline__ unsigned int permb(unsigned int a, unsigned int b, unsigned int s)
{
    return __builtin_amdgcn_perm(a, b, s);
}
__device__ __forceinline__ float fdot2u(unsigned int a, unsigned int b, float c)
{
    union { unsigned int u; half2v h; } x, y;
    x.u = a; y.u = b;
    return __builtin_amdgcn_fdot2(x.h, y.h, c, false);
}

__device__ __forceinline__ int load_idx(const int* ei32, int is64, int pos)
{
    return is64 ? ei32[2 * pos] : ei32[pos];
}

// ---------------- fused prep: detect + watt + weight bf16 conversion ----------------
__global__ __launch_bounds__(256) void prep_kernel(const float* __restrict__ W,
                                                   const float* __restrict__ att_s,
                                                   const float* __restrict__ att_d,
                                                   const float* __restrict__ lin_w,
                                                   const int* __restrict__ ei32,
                                                   float* __restrict__ was,
                                                   float* __restrict__ wad,
                                                   unsigned short* __restrict__ Wb,
                                                   unsigned short* __restrict__ linwb,
                                                   int* __restrict__ flag)
{
    int b = blockIdx.x, t = threadIdx.x;
    if (b == 0) {
        if (t < 64) {
            int v = ei32[2 * t + 1];
            unsigned long long m = __ballot(v != 0);
            if (t == 0) *flag = (m == 0ull) ? 1 : 0;
        }
    } else if (b <= 2) {
        int hd = b - 1;
        float as = 0.f, ad = 0.f;
        for (int c = 0; c < CCOUT; c++) {
            float wv = W[(size_t)(hd * CCOUT + c) * FIN + t];
            as += att_s[hd * CCOUT + c] * wv;
            ad += att_d[hd * CCOUT + c] * wv;
        }
        was[hd * FIN + t] = as;
        wad[hd * FIN + t] = ad;
    } else if (b < 3 + PREP_W_BLOCKS) {
        int i = (b - 3) * 256 + t;
        float4 v = *(const float4*)(W + (size_t)i * 4);
        ushort4 o;
        o.x = f2bf(v.x); o.y = f2bf(v.y); o.z = f2bf(v.z); o.w = f2bf(v.w);
        *(ushort4*)(Wb + (size_t)i * 4) = o;
    } else {
        int i = (b - 3 - PREP_W_BLOCKS) * 256 + t;
        float4 v = *(const float4*)(lin_w + (size_t)i * 4);
        ushort4 o;
        o.x = f2bf(v.x); o.y = f2bf(v.y); o.z = f2bf(v.z); o.w = f2bf(v.w);
        *(ushort4*)(linwb + (size_t)i * 4) = o;
    }
}

// ---------------- fused: x->bf16 + fp32 attention logits || count (8 edges/thread) ----
// R7: back to R4 structure (eord via atomicAdd-return in the count phase; the
// scatter reads it as a plain load). Count unrolled 4->8 edges/thread: 8
// independent atomic->eord chains in flight halves the number of serialized
// latency epochs in the count tail. (R6 showed moving the with-return atomic
// into the scatter costs more; R4/R5 showed placement of count blocks is noise.)
__global__ __launch_bounds__(256) void xprep_count_kernel(const float* __restrict__ x,
                                                          const float* __restrict__ was,
                                                          const float* __restrict__ wad,
                                                          unsigned short* __restrict__ xb,
                                                          float* __restrict__ a_s,
                                                          float* __restrict__ a_d,
                                                          const int* __restrict__ ei32,
                                                          const int* __restrict__ flag,
                                                          int* __restrict__ deg,
                                                          int* __restrict__ eord)
{
    int b = blockIdx.x, t = threadIdx.x;
    if (b < NB_XPREP) {
        int w = t >> 6, l = t & 63;
        int n = b * 4 + w;
        float4 xv = *(const float4*)(x + (size_t)n * FIN + l * 4);
        ushort4 xs;
        xs.x = f2bf(xv.x); xs.y = f2bf(xv.y); xs.z = f2bf(xv.z); xs.w = f2bf(xv.w);
        *(ushort4*)(xb + (size_t)n * FIN + l * 4) = xs;

        float4 s0 = *(const float4*)(was + l * 4);
        float4 s1 = *(const float4*)(was + FIN + l * 4);
        float4 d0 = *(const float4*)(wad + l * 4);
        float4 d1 = *(const float4*)(wad + FIN + l * 4);
        float vs0 = xv.x * s0.x + xv.y * s0.y + xv.z * s0.z + xv.w * s0.w;
        float vs1 = xv.x * s1.x + xv.y * s1.y + xv.z * s1.z + xv.w * s1.w;
        float vd0 = xv.x * d0.x + xv.y * d0.y + xv.z * d0.z + xv.w * d0.w;
        float vd1 = xv.x * d1.x + xv.y * d1.y + xv.z * d1.z + xv.w * d1.w;
#pragma unroll
        for (int off = 32; off > 0; off >>= 1) {
            vs0 += __shfl_down(vs0, off);
            vs1 += __shfl_down(vs1, off);
            vd0 += __shfl_down(vd0, off);
            vd1 += __shfl_down(vd1, off);
        }
        if (l == 0) {
            a_s[n * 2 + 0] = vs0; a_s[n * 2 + 1] = vs1;
            a_d[n * 2 + 0] = vd0; a_d[n * 2 + 1] = vd1;
        }
    } else {
        int base = (b - NB_XPREP) * 2048 + t;
        int is64 = *flag;
        int dd[8];
        int rr[8];
#pragma unroll
        for (int k = 0; k < 8; k++) {
            int e = base + k * 256;
            dd[k] = -1;
            if (e < ET) dd[k] = (e < EE) ? load_idx(ei32, is64, EE + e) : (e - EE);
        }
#pragma unroll
        for (int k = 0; k < 8; k++)
            rr[k] = (dd[k] >= 0) ? atomicAdd(&deg[dd[k]], 1) : 0;
#pragma unroll
        for (int k = 0; k < 8; k++)
            if (dd[k] >= 0) eord[base + k * 256] = rr[k];
    }
}

// ---------------- MFMA bf16 GEMM (standalone, used for GEMM2) ----------------
template <bool ADD_BIAS, bool OUT_BF16>
__global__ __launch_bounds__(256) void gemm_mfma(const unsigned short* __restrict__ A,
                                                 const unsigned short* __restrict__ B,
                                                 const float* __restrict__ bias,
                                                 void* __restrict__ Cout,
                                                 int M, int N, int K)
{
    const int LDT = 40;
    __shared__ unsigned short As[128 * LDT];
    __shared__ unsigned short Bs[128 * LDT];

    int tid = threadIdx.x;
    int wave = tid >> 6, lane = tid & 63;
    int wr = wave >> 1, wc = wave & 1;
    int quad = lane >> 4, l16 = lane & 15;
    int bm0 = blockIdx.x * 128;
    int bn0 = blockIdx.y * 128;

    floatx4 acc[4][4] = {};

    for (int kk = 0; kk < K; kk += 32) {
#pragma unroll
        for (int p = 0; p < 2; p++) {
            int idx = p * 256 + tid;
            int row = idx >> 2, seg = idx & 3;
            int grow = bm0 + row; if (grow >= M) grow = M - 1;
            uint4 va = *(const uint4*)(A + (size_t)grow * K + kk + seg * 8);
            *(uint4*)(&As[row * LDT + seg * 8]) = va;
            uint4 vb = *(const uint4*)(B + (size_t)(bn0 + row) * K + kk + seg * 8);
            *(uint4*)(&Bs[row * LDT + seg * 8]) = vb;
        }
        __syncthreads();

        short8 af[4], bfr[4];
#pragma unroll
        for (int mi = 0; mi < 4; mi++)
            af[mi] = *(const short8*)(&As[(wr * 64 + mi * 16 + l16) * LDT + quad * 8]);
#pragma unroll
        for (int ni = 0; ni < 4; ni++)
            bfr[ni] = *(const short8*)(&Bs[(wc * 64 + ni * 16 + l16) * LDT + quad * 8]);
#pragma unroll
        for (int mi = 0; mi < 4; mi++)
#pragma unroll
            for (int ni = 0; ni < 4; ni++)
                acc[mi][ni] = __builtin_amdgcn_mfma_f32_16x16x32_bf16(af[mi], bfr[ni], acc[mi][ni], 0, 0, 0);
        __syncthreads();
    }

#pragma unroll
    for (int mi = 0; mi < 4; mi++) {
#pragma unroll
        for (int ni = 0; ni < 4; ni++) {
            int col = bn0 + wc * 64 + ni * 16 + l16;
#pragma unroll
            for (int r = 0; r < 4; r++) {
                int row = bm0 + wr * 64 + mi * 16 + quad * 4 + r;
                if (row < M) {
                    float v = acc[mi][ni][r];
                    if (ADD_BIAS) v += bias[col];
                    if (OUT_BF16)
                        ((unsigned short*)Cout)[(size_t)row * N + col] = f2bf(v);
                    else
                        ((float*)Cout)[(size_t)row * N + col] = v;
                }
            }
        }
    }
}

// ---------------- FUSED: scatter (latency-bound) + GEMM1 (MFMA-bound), interleaved 4:1 ----
// GEMM1 writes hb row-major [NN][HC] as FP16 (agg consumes it via v_dot2_f32_f16).
__global__ __launch_bounds__(256) void scatter_gemm1_kernel(
        const int* __restrict__ ei32, const int* __restrict__ flag,
        const int* __restrict__ eord, const int* __restrict__ rowstart,
        const float* __restrict__ a_s, const float* __restrict__ a_d,
        uint2* __restrict__ rec,
        const unsigned short* __restrict__ A,   // xb [NN, FIN]
        const unsigned short* __restrict__ B,   // Wb [HC, FIN]
        unsigned short* __restrict__ hb)        // out [NN, HC] fp16
{
    const int LDT = 40;
    __shared__ unsigned short As[128 * LDT];
    __shared__ unsigned short Bs[128 * LDT];

    int b = blockIdx.x, tid = threadIdx.x;
    int sb = -1, gb = -1;
    if (b < FUSE_HEAD) {
        int g = b / 5, r = b - g * 5;
        if (r < 4) sb = g * 4 + r; else gb = g;
    } else {
        sb = SCAT_IN_HEAD + (b - FUSE_HEAD);
    }

    if (sb >= 0) {
        int e = sb * 256 + tid;
        if (e < ET) {
            int is64 = *flag;
            int s, d;
            if (e < EE) { s = load_idx(ei32, is64, e); d = load_idx(ei32, is64, EE + e); }
            else { s = d = e - EE; }
            float e0 = a_s[s * 2 + 0] + a_d[d * 2 + 0];
            float e1 = a_s[s * 2 + 1] + a_d[d * 2 + 1];
            e0 = e0 > 0.f ? e0 : NEG * e0;
            e1 = e1 > 0.f ? e1 : NEG * e1;
            __half2 hp = __floats2half2_rn(__expf(e0), __expf(e1));
            uint2 r;
            r.x = (unsigned int)s;
            r.y = *(unsigned int*)&hp;
            rec[rowstart[d] + eord[e]] = r;
        }
        return;
    }

    int bx = gb % G1X, by = gb / G1X;
    int wave = tid >> 6, lane = tid & 63;
    int wr = wave >> 1, wc = wave & 1;
    int quad = lane >> 4, l16 = lane & 15;
    int bm0 = bx * 128;
    int bn0 = by * 128;

    floatx4 acc[4][4] = {};

    for (int kk = 0; kk < FIN; kk += 32) {
#pragma unroll
        for (int p = 0; p < 2; p++) {
            int idx = p * 256 + tid;
            int row = idx >> 2, seg = idx & 3;
            int grow = bm0 + row; if (grow >= NN) grow = NN - 1;
            uint4 va = *(const uint4*)(A + (size_t)grow * FIN + kk + seg * 8);
            *(uint4*)(&As[row * LDT + seg * 8]) = va;
            uint4 vb = *(const uint4*)(B + (size_t)(bn0 + row) * FIN + kk + seg * 8);
            *(uint4*)(&Bs[row * LDT + seg * 8]) = vb;
        }
        __syncthreads();

        short8 af[4], bfr[4];
#pragma unroll
        for (int mi = 0; mi < 4; mi++)
            af[mi] = *(const short8*)(&As[(wr * 64 + mi * 16 + l16) * LDT + quad * 8]);
#pragma unroll
        for (int ni = 0; ni < 4; ni++)
            bfr[ni] = *(const short8*)(&Bs[(wc * 64 + ni * 16 + l16) * LDT + quad * 8]);
#pragma unroll
        for (int mi = 0; mi < 4; mi++)
#pragma unroll
            for (int ni = 0; ni < 4; ni++)
                acc[mi][ni] = __builtin_amdgcn_mfma_f32_16x16x32_bf16(af[mi], bfr[ni], acc[mi][ni], 0, 0, 0);
        __syncthreads();
    }

#pragma unroll
    for (int mi = 0; mi < 4; mi++) {
#pragma unroll
        for (int ni = 0; ni < 4; ni++) {
            int col = bn0 + wc * 64 + ni * 16 + l16;
#pragma unroll
            for (int r = 0; r < 4; r++) {
                int row = bm0 + wr * 64 + mi * 16 + quad * 4 + r;
                if (row < NN)
                    hb[(size_t)row * HC + col] = f2h(acc[mi][ni][r]);
            }
        }
    }
}

// ---------------- scan1: per-block inclusive scan + block totals ----------------
__global__ __launch_bounds__(256) void scan1(const int* __restrict__ deg,
                                             int* __restrict__ tmp, int* __restrict__ bsum)
{
    __shared__ int s[256];
    int i = blockIdx.x * 256 + threadIdx.x;
    int v = (i < NN) ? deg[i] : 0;
    s[threadIdx.x] = v;
    __syncthreads();
    for (int off = 1; off < 256; off <<= 1) {
        int add = (threadIdx.x >= off) ? s[threadIdx.x - off] : 0;
        __syncthreads();
        s[threadIdx.x] += add;
        __syncthreads();
    }
    if (i < NN) tmp[i] = s[threadIdx.x];
    if (threadIdx.x == 255) bsum[blockIdx.x] = s[255];
}

// ---------------- scan2+scan3 fused ----------------
__global__ __launch_bounds__(256) void scan23(const int* __restrict__ deg,
                                              const int* __restrict__ tmp,
                                              const int* __restrict__ bsum,
                                              int* __restrict__ rowstart)
{
    __shared__ int s[256];
    int b = blockIdx.x, t = threadIdx.x;
    int v = (t < NB_SCAN && t < b) ? bsum[t] : 0;
    s[t] = v;
    __syncthreads();
#pragma unroll
    for (int off = 128; off > 0; off >>= 1) {
        if (t < off) s[t] += s[t + off];
        __syncthreads();
    }
    int offset = s[0];
    int i = b * 256 + t;
    if (i < NN) rowstart[i] = tmp[i] - deg[i] + offset;
    if (i == 0) rowstart[NN] = ET;
}

// ---------------- gather-aggregate v11: agg7 structure + v_perm/v_dot2_f32_f16 ----
// wave per node, half-wave edge interleave, 4 gather chains in flight (8 edges/wave-iter).
// Channel math: pair two edges; v_perm packs (h_e0[c], h_e1[c]) as half2; one
// v_dot2_f32_f16 does both MACs. Tail zero-fill uses perm selector 0x0C
// (constant 0x00) -- NOT 0x80 (0xFF-class -> fp16 NaN, R3 failure).
// NOTE (R5 counters): memory-path-bound; FETCH 187MB = compulsory traffic for
// random dest->XCD dispatch (44k distinct 512B rows per XCD x 8). VALU cuts
// don't move it; XCD-pinned chunking loses more on MLP (R1/R2). Parked.
__global__ __launch_bounds__(256) void agg11_kernel(const unsigned short* __restrict__ hb,
                                                    const int* __restrict__ rowstart,
                                                    const uint2* __restrict__ rec,
                                                    const float* __restrict__ bias,
                                                    unsigned short* __restrict__ aggb)
{
    int wave = threadIdx.x >> 6, lane = threadIdx.x & 63;
    int d = blockIdx.x * 4 + wave;
    int half = lane >> 5;
    int l = lane & 31;
    int c = l * 8;
    // lanes 0-15: head0 (p = bytes 0-1 of rec.y), lanes 16-31: head1 (bytes 2-3)
    unsigned int selp  = (l & 16) ? 0x07060302u : 0x05040100u;
    unsigned int selps = (l & 16) ? 0x0C0C0302u : 0x0C0C0100u;   // (p, +0.0)
    const unsigned int ones = 0x3C003C00u;   // half2(1.0, 1.0)
    const unsigned long long* recq = (const unsigned long long*)rec;

    int j0 = rowstart[d], j1 = rowstart[d + 1];
    float a0 = 0.f, a1 = 0.f, a2 = 0.f, a3 = 0.f;
    float a4 = 0.f, a5 = 0.f, a6 = 0.f, a7 = 0.f;
    float psum = 0.f;

    int j = j0 + half;
    // 4 edges per half per iter (2 dot2-pairs), 4 gathers in flight
    for (; j + 6 < j1; j += 8) {
        unsigned long long q0 = recq[j], q1 = recq[j + 2], q2 = recq[j + 4], q3 = recq[j + 6];
        unsigned int pp01 = permb((unsigned int)(q1 >> 32), (unsigned int)(q0 >> 32), selp);
        unsigned int pp23 = permb((unsigned int)(q3 >> 32), (unsigned int)(q2 >> 32), selp);
        psum = fdot2u(pp01, ones, psum);
        psum = fdot2u(pp23, ones, psum);
        uint4 h0 = *(const uint4*)(hb + (size_t)(unsigned int)q0 * HC + c);
        uint4 h1 = *(const uint4*)(hb + (size_t)(unsigned int)q1 * HC + c);
        uint4 h2 = *(const uint4*)(hb + (size_t)(unsigned int)q2 * HC + c);
        uint4 h3 = *(const uint4*)(hb + (size_t)(unsigned int)q3 * HC + c);
        a0 = fdot2u(permb(h1.x, h0.x, 0x05040100u), pp01, a0);
        a0 = fdot2u(permb(h3.x, h2.x, 0x05040100u), pp23, a0);
        a1 = fdot2u(permb(h1.x, h0.x, 0x07060302u), pp01, a1);
        a1 = fdot2u(permb(h3.x, h2.x, 0x07060302u), pp23, a1);
        a2 = fdot2u(permb(h1.y, h0.y, 0x05040100u), pp01, a2);
        a2 = fdot2u(permb(h3.y, h2.y, 0x05040100u), pp23, a2);
        a3 = fdot2u(permb(h1.y, h0.y, 0x07060302u), pp01, a3);
        a3 = fdot2u(permb(h3.y, h2.y, 0x07060302u), pp23, a3);
        a4 = fdot2u(permb(h1.z, h0.z, 0x05040100u), pp01, a4);
        a4 = fdot2u(permb(h3.z, h2.z, 0x05040100u), pp23, a4);
        a5 = fdot2u(permb(h1.z, h0.z, 0x07060302u), pp01, a5);
        a5 = fdot2u(permb(h3.z, h2.z, 0x07060302u), pp23, a5);
        a6 = fdot2u(permb(h1.w, h0.w, 0x05040100u), pp01, a6);
        a6 = fdot2u(permb(h3.w, h2.w, 0x05040100u), pp23, a6);
        a7 = fdot2u(permb(h1.w, h0.w, 0x07060302u), pp01, a7);
        a7 = fdot2u(permb(h3.w, h2.w, 0x07060302u), pp23, a7);
    }
    // tail: one edge per half per iter, zero-padded pair (selector 0x0C = 0x00)
    for (; j < j1; j += 2) {
        unsigned long long q0 = recq[j];
        unsigned int pp = permb(0u, (unsigned int)(q0 >> 32), selps);
        psum = fdot2u(pp, ones, psum);
        uint4 h0 = *(const uint4*)(hb + (size_t)(unsigned int)q0 * HC + c);
        a0 = fdot2u(permb(0u, h0.x, 0x0C0C0100u), pp, a0);
        a1 = fdot2u(permb(0u, h0.x, 0x0C0C0302u), pp, a1);
        a2 = fdot2u(permb(0u, h0.y, 0x0C0C0100u), pp, a2);
        a3 = fdot2u(permb(0u, h0.y, 0x0C0C0302u), pp, a3);
        a4 = fdot2u(permb(0u, h0.z, 0x0C0C0100u), pp, a4);
        a5 = fdot2u(permb(0u, h0.z, 0x0C0C0302u), pp, a5);
        a6 = fdot2u(permb(0u, h0.w, 0x0C0C0100u), pp, a6);
        a7 = fdot2u(permb(0u, h0.w, 0x0C0C0302u), pp, a7);
    }

    a0 += __shfl_xor(a0, 32);
    a1 += __shfl_xor(a1, 32);
    a2 += __shfl_xor(a2, 32);
    a3 += __shfl_xor(a3, 32);
    a4 += __shfl_xor(a4, 32);
    a5 += __shfl_xor(a5, 32);
    a6 += __shfl_xor(a6, 32);
    a7 += __shfl_xor(a7, 32);
    psum += __shfl_xor(psum, 32);

    if (half == 0) {
        float inv = 1.f / fmaxf(psum, 1e-16f);
        float4 b0 = *(const float4*)(bias + c);
        float4 b1 = *(const float4*)(bias + c + 4);
        float v0 = a0 * inv + b0.x;
        float v1 = a1 * inv + b0.y;
        float v2 = a2 * inv + b0.z;
        float v3 = a3 * inv + b0.w;
        float v4 = a4 * inv + b1.x;
        float v5 = a5 * inv + b1.y;
        float v6 = a6 * inv + b1.z;
        float v7 = a7 * inv + b1.w;
        v0 = v0 > 0.f ? v0 : expm1f(v0);
        v1 = v1 > 0.f ? v1 : expm1f(v1);
        v2 = v2 > 0.f ? v2 : expm1f(v2);
        v3 = v3 > 0.f ? v3 : expm1f(v3);
        v4 = v4 > 0.f ? v4 : expm1f(v4);
        v5 = v5 > 0.f ? v5 : expm1f(v5);
        v6 = v6 > 0.f ? v6 : expm1f(v6);
        v7 = v7 > 0.f ? v7 : expm1f(v7);
        uint4 o;
        o.x = (unsigned int)f2bf(v0) | ((unsigned int)f2bf(v1) << 16);
        o.y = (unsigned int)f2bf(v2) | ((unsigned int)f2bf(v3) << 16);
        o.z = (unsigned int)f2bf(v4) | ((unsigned int)f2bf(v5) << 16);
        o.w = (unsigned int)f2bf(v6) | ((unsigned int)f2bf(v7) << 16);
        *(uint4*)(aggb + (size_t)d * HC + c) = o;
    }
}

// ---------------- launch ----------------
extern "C" void kernel_launch(void* const* d_in, const int* in_sizes, int n_in,
                              void* d_out, int out_size, void* d_ws, size_t ws_size,
                              hipStream_t stream)
{
    const float* x       = (const float*)d_in[0];
    const int*   ei32    = (const int*)d_in[1];
    const float* W       = (const float*)d_in[2];
    const float* att_src = (const float*)d_in[3];
    const float* att_dst = (const float*)d_in[4];
    const float* bias    = (const float*)d_in[5];
    const float* lin_w   = (const float*)d_in[6];
    const float* lin_b   = (const float*)d_in[7];
    float* out = (float*)d_out;

    char* ws = (char*)d_ws;
    size_t off = 0;
    auto alloc = [&](size_t bytes) -> void* {
        void* p = ws + off;
        off += (bytes + 255) & ~(size_t)255;
        return p;
    };

    // zero-init region first (deg only)
    int*   deg    = (int*)alloc((size_t)NN * 4);
    size_t zero_bytes = off;

    int*   flag     = (int*)alloc(256);
    int*   tmp      = (int*)alloc((size_t)NN * 4);
    int*   bsum     = (int*)alloc(1024);
    int*   rowstart = (int*)alloc((size_t)(NN + 1) * 4);
    int*   eord     = (int*)alloc((size_t)ET * 4);
    float* was      = (float*)alloc((size_t)HH * FIN * 4);
    float* wad      = (float*)alloc((size_t)HH * FIN * 4);
    float* a_s      = (float*)alloc((size_t)NN * 2 * 4);
    float* a_d      = (float*)alloc((size_t)NN * 2 * 4);
    uint2* rec      = (uint2*)alloc((size_t)ET * 8);
    unsigned short* xb     = (unsigned short*)alloc((size_t)NN * FIN * 2);
    unsigned short* Wb     = (unsigned short*)alloc((size_t)HC * FIN * 2);
    unsigned short* linwb  = (unsigned short*)alloc((size_t)CCOUT * HC * 2);
    unsigned short* hb     = (unsigned short*)alloc((size_t)NN * HC * 2);   // fp16 [NN][HC]
    unsigned short* aggb   = (unsigned short*)alloc((size_t)NN * HC * 2);   // bf16 [NN][HC]

    hipMemsetAsync(d_ws, 0, zero_bytes, stream);

    prep_kernel<<<PREP_GRID, 256, 0, stream>>>(W, att_src, att_dst, lin_w, ei32,
                                               was, wad, Wb, linwb, flag);

    xprep_count_kernel<<<NB_XPREP + NB_EDGE8, 256, 0, stream>>>(x, was, wad, xb, a_s, a_d,
                                                                ei32, flag, deg, eord);

    scan1<<<NB_SCAN, 256, 0, stream>>>(deg, tmp, bsum);
    scan23<<<NB_SCAN, 256, 0, stream>>>(deg, tmp, bsum, rowstart);

    scatter_gemm1_kernel<<<NB_FUSE, 256, 0, stream>>>(ei32, flag, eord, rowstart,
                                                      a_s, a_d, rec, xb, Wb, hb);

    agg11_kernel<<<NN / 4, 256, 0, stream>>>(hb, rowstart, rec, bias, aggb);

    dim3 g2((NN + 127) / 128, CCOUT / 128);
    gemm_mfma<true, false><<<g2, 256, 0, stream>>>(aggb, linwb, lin_b, out, NN, CCOUT, HC);
}

// Round 8
// 258.346 us; speedup vs baseline: 1.0960x; 1.0647x over previous
//
#include <hip/hip_runtime.h>
#include <hip/hip_fp16.h>
#include <math.h>

#define NN 50000
#define EE 800000
#define ET (EE + NN)
#define FIN 256
#define CCOUT 128
#define HH 2
#define HC 256
#define NEG 0.2f
#define RCAP 64                          // slots per dst bucket; P(deg>=64) ~ 3e-17

#define NB_XPREP (NN / 4)

// prep grid: 1 detect + 2 watt + 64 W-conv + 32 linw-conv
#define PREP_W_BLOCKS 64
#define PREP_LW_BLOCKS 32
#define PREP_GRID (3 + PREP_W_BLOCKS + PREP_LW_BLOCKS)

// fused scatter+gemm1: scatter 4 edges/thread (831 blocks) 1:1-interleaved with
// 782 gemm blocks, then 49 scatter tail blocks.
#define G1X 391                          // (NN+127)/128
#define G1Y 2                            // HC/128
#define NB_G1 (G1X * G1Y)                // 782
#define NB_SCAT4 ((ET + 1023) / 1024)    // 831
#define PAIR_HEAD (2 * NB_G1)            // 1564
#define NB_FUSE2 (NB_SCAT4 + NB_G1)      // 1613

typedef __attribute__((ext_vector_type(8))) short short8;
typedef __attribute__((ext_vector_type(4))) float floatx4;
typedef _Float16 half2v __attribute__((ext_vector_type(2)));

// ---------------- helpers ----------------
__device__ __forceinline__ unsigned short f2bf(float f)
{
    union { float f; unsigned int u; } x; x.f = f;
    unsigned int r = x.u + 0x7fffu + ((x.u >> 16) & 1u);   // RNE
    return (unsigned short)(r >> 16);
}
__device__ __forceinline__ unsigned short f2h(float f)
{
    __half h = __float2half_rn(f);
    return *(const unsigned short*)&h;
}
__device__ __forceinline__ unsigned int permb(unsigned int a, unsigned int b, unsigned int s)
{
    return __builtin_amdgcn_perm(a, b, s);
}
__device__ __forceinline__ float fdot2u(unsigned int a, unsigned int b, float c)
{
    union { unsigned int u; half2v h; } x, y;
    x.u = a; y.u = b;
    return __builtin_amdgcn_fdot2(x.h, y.h, c, false);
}

__device__ __forceinline__ int load_idx(const int* ei32, int is64, int pos)
{
    return is64 ? ei32[2 * pos] : ei32[pos];
}

// ---------------- fused prep: detect + watt + weight bf16 conversion ----------------
__global__ __launch_bounds__(256) void prep_kernel(const float* __restrict__ W,
                                                   const float* __restrict__ att_s,
                                                   const float* __restrict__ att_d,
                                                   const float* __restrict__ lin_w,
                                                   const int* __restrict__ ei32,
                                                   float* __restrict__ was,
                                                   float* __restrict__ wad,
                                                   unsigned short* __restrict__ Wb,
                                                   unsigned short* __restrict__ linwb,
                                                   int* __restrict__ flag)
{
    int b = blockIdx.x, t = threadIdx.x;
    if (b == 0) {
        if (t < 64) {
            int v = ei32[2 * t + 1];
            unsigned long long m = __ballot(v != 0);
            if (t == 0) *flag = (m == 0ull) ? 1 : 0;
        }
    } else if (b <= 2) {
        int hd = b - 1;
        float as = 0.f, ad = 0.f;
        for (int c = 0; c < CCOUT; c++) {
            float wv = W[(size_t)(hd * CCOUT + c) * FIN + t];
            as += att_s[hd * CCOUT + c] * wv;
            ad += att_d[hd * CCOUT + c] * wv;
        }
        was[hd * FIN + t] = as;
        wad[hd * FIN + t] = ad;
    } else if (b < 3 + PREP_W_BLOCKS) {
        int i = (b - 3) * 256 + t;
        float4 v = *(const float4*)(W + (size_t)i * 4);
        ushort4 o;
        o.x = f2bf(v.x); o.y = f2bf(v.y); o.z = f2bf(v.z); o.w = f2bf(v.w);
        *(ushort4*)(Wb + (size_t)i * 4) = o;
    } else {
        int i = (b - 3 - PREP_W_BLOCKS) * 256 + t;
        float4 v = *(const float4*)(lin_w + (size_t)i * 4);
        ushort4 o;
        o.x = f2bf(v.x); o.y = f2bf(v.y); o.z = f2bf(v.z); o.w = f2bf(v.w);
        *(ushort4*)(linwb + (size_t)i * 4) = o;
    }
}

// ---------------- xprep: x->bf16 + fp32 attention logits (pure streaming) ----------------
// R8: count pass DELETED (fixed-capacity buckets). This kernel is now pure
// throughput: 51MB read + 29MB write.
__global__ __launch_bounds__(256) void xprep_kernel(const float* __restrict__ x,
                                                    const float* __restrict__ was,
                                                    const float* __restrict__ wad,
                                                    unsigned short* __restrict__ xb,
                                                    float* __restrict__ a_s,
                                                    float* __restrict__ a_d)
{
    int b = blockIdx.x, t = threadIdx.x;
    int w = t >> 6, l = t & 63;
    int n = b * 4 + w;
    float4 xv = *(const float4*)(x + (size_t)n * FIN + l * 4);
    ushort4 xs;
    xs.x = f2bf(xv.x); xs.y = f2bf(xv.y); xs.z = f2bf(xv.z); xs.w = f2bf(xv.w);
    *(ushort4*)(xb + (size_t)n * FIN + l * 4) = xs;

    float4 s0 = *(const float4*)(was + l * 4);
    float4 s1 = *(const float4*)(was + FIN + l * 4);
    float4 d0 = *(const float4*)(wad + l * 4);
    float4 d1 = *(const float4*)(wad + FIN + l * 4);
    float vs0 = xv.x * s0.x + xv.y * s0.y + xv.z * s0.z + xv.w * s0.w;
    float vs1 = xv.x * s1.x + xv.y * s1.y + xv.z * s1.z + xv.w * s1.w;
    float vd0 = xv.x * d0.x + xv.y * d0.y + xv.z * d0.z + xv.w * d0.w;
    float vd1 = xv.x * d1.x + xv.y * d1.y + xv.z * d1.z + xv.w * d1.w;
#pragma unroll
    for (int off = 32; off > 0; off >>= 1) {
        vs0 += __shfl_down(vs0, off);
        vs1 += __shfl_down(vs1, off);
        vd0 += __shfl_down(vd0, off);
        vd1 += __shfl_down(vd1, off);
    }
    if (l == 0) {
        a_s[n * 2 + 0] = vs0; a_s[n * 2 + 1] = vs1;
        a_d[n * 2 + 0] = vd0; a_d[n * 2 + 1] = vd1;
    }
}

// ---------------- MFMA bf16 GEMM (standalone, used for GEMM2) ----------------
template <bool ADD_BIAS, bool OUT_BF16>
__global__ __launch_bounds__(256) void gemm_mfma(const unsigned short* __restrict__ A,
                                                 const unsigned short* __restrict__ B,
                                                 const float* __restrict__ bias,
                                                 void* __restrict__ Cout,
                                                 int M, int N, int K)
{
    const int LDT = 40;
    __shared__ unsigned short As[128 * LDT];
    __shared__ unsigned short Bs[128 * LDT];

    int tid = threadIdx.x;
    int wave = tid >> 6, lane = tid & 63;
    int wr = wave >> 1, wc = wave & 1;
    int quad = lane >> 4, l16 = lane & 15;
    int bm0 = blockIdx.x * 128;
    int bn0 = blockIdx.y * 128;

    floatx4 acc[4][4] = {};

    for (int kk = 0; kk < K; kk += 32) {
#pragma unroll
        for (int p = 0; p < 2; p++) {
            int idx = p * 256 + tid;
            int row = idx >> 2, seg = idx & 3;
            int grow = bm0 + row; if (grow >= M) grow = M - 1;
            uint4 va = *(const uint4*)(A + (size_t)grow * K + kk + seg * 8);
            *(uint4*)(&As[row * LDT + seg * 8]) = va;
            uint4 vb = *(const uint4*)(B + (size_t)(bn0 + row) * K + kk + seg * 8);
            *(uint4*)(&Bs[row * LDT + seg * 8]) = vb;
        }
        __syncthreads();

        short8 af[4], bfr[4];
#pragma unroll
        for (int mi = 0; mi < 4; mi++)
            af[mi] = *(const short8*)(&As[(wr * 64 + mi * 16 + l16) * LDT + quad * 8]);
#pragma unroll
        for (int ni = 0; ni < 4; ni++)
            bfr[ni] = *(const short8*)(&Bs[(wc * 64 + ni * 16 + l16) * LDT + quad * 8]);
#pragma unroll
        for (int mi = 0; mi < 4; mi++)
#pragma unroll
            for (int ni = 0; ni < 4; ni++)
                acc[mi][ni] = __builtin_amdgcn_mfma_f32_16x16x32_bf16(af[mi], bfr[ni], acc[mi][ni], 0, 0, 0);
        __syncthreads();
    }

#pragma unroll
    for (int mi = 0; mi < 4; mi++) {
#pragma unroll
        for (int ni = 0; ni < 4; ni++) {
            int col = bn0 + wc * 64 + ni * 16 + l16;
#pragma unroll
            for (int r = 0; r < 4; r++) {
                int row = bm0 + wr * 64 + mi * 16 + quad * 4 + r;
                if (row < M) {
                    float v = acc[mi][ni][r];
                    if (ADD_BIAS) v += bias[col];
                    if (OUT_BF16)
                        ((unsigned short*)Cout)[(size_t)row * N + col] = f2bf(v);
                    else
                        ((float*)Cout)[(size_t)row * N + col] = v;
                }
            }
        }
    }
}

// ---------------- FUSED: scatter (rank-atomic, 4 edges/thread) + GEMM1, 1:1 ----
// R8: rank = atomicAdd(&cnt[d],1) assigns a slot in d's fixed 64-slot bucket.
// 4 independent atomic chains/thread; latency hides under co-resident GEMM1
// MFMA blocks. No count pass, no scans -- cnt doubles as deg for agg.
__global__ __launch_bounds__(256) void scatter_gemm1_kernel(
        const int* __restrict__ ei32, const int* __restrict__ flag,
        int* __restrict__ cnt,
        const float* __restrict__ a_s, const float* __restrict__ a_d,
        uint2* __restrict__ rec,
        const unsigned short* __restrict__ A,   // xb [NN, FIN]
        const unsigned short* __restrict__ B,   // Wb [HC, FIN]
        unsigned short* __restrict__ hb)        // out [NN, HC] fp16
{
    const int LDT = 40;
    __shared__ unsigned short As[128 * LDT];
    __shared__ unsigned short Bs[128 * LDT];

    int b = blockIdx.x, tid = threadIdx.x;
    int sb = -1, gb = -1;
    if (b < PAIR_HEAD) {
        if (b & 1) sb = b >> 1; else gb = b >> 1;
    } else {
        sb = NB_G1 + (b - PAIR_HEAD);
    }

    if (sb >= 0) {
        int base = sb * 1024 + tid;
        int is64 = *flag;
        int ss[4], dd[4];
#pragma unroll
        for (int k = 0; k < 4; k++) {
            int e = base + k * 256;
            ss[k] = -1; dd[k] = 0;
            if (e < ET) {
                if (e < EE) { ss[k] = load_idx(ei32, is64, e); dd[k] = load_idx(ei32, is64, EE + e); }
                else { ss[k] = dd[k] = e - EE; }
            }
        }
        int rk[4];
#pragma unroll
        for (int k = 0; k < 4; k++)
            rk[k] = (ss[k] >= 0) ? atomicAdd(&cnt[dd[k]], 1) : 0;
#pragma unroll
        for (int k = 0; k < 4; k++) {
            if (ss[k] < 0) continue;
            float e0 = a_s[ss[k] * 2 + 0] + a_d[dd[k] * 2 + 0];
            float e1 = a_s[ss[k] * 2 + 1] + a_d[dd[k] * 2 + 1];
            e0 = e0 > 0.f ? e0 : NEG * e0;
            e1 = e1 > 0.f ? e1 : NEG * e1;
            __half2 hp = __floats2half2_rn(__expf(e0), __expf(e1));
            uint2 r;
            r.x = (unsigned int)ss[k];
            r.y = *(unsigned int*)&hp;
            if (rk[k] < RCAP)
                rec[(size_t)dd[k] * RCAP + rk[k]] = r;
        }
        return;
    }

    int bx = gb % G1X, by = gb / G1X;
    int wave = tid >> 6, lane = tid & 63;
    int wr = wave >> 1, wc = wave & 1;
    int quad = lane >> 4, l16 = lane & 15;
    int bm0 = bx * 128;
    int bn0 = by * 128;

    floatx4 acc[4][4] = {};

    for (int kk = 0; kk < FIN; kk += 32) {
#pragma unroll
        for (int p = 0; p < 2; p++) {
            int idx = p * 256 + tid;
            int row = idx >> 2, seg = idx & 3;
            int grow = bm0 + row; if (grow >= NN) grow = NN - 1;
            uint4 va = *(const uint4*)(A + (size_t)grow * FIN + kk + seg * 8);
            *(uint4*)(&As[row * LDT + seg * 8]) = va;
            uint4 vb = *(const uint4*)(B + (size_t)(bn0 + row) * FIN + kk + seg * 8);
            *(uint4*)(&Bs[row * LDT + seg * 8]) = vb;
        }
        __syncthreads();

        short8 af[4], bfr[4];
#pragma unroll
        for (int mi = 0; mi < 4; mi++)
            af[mi] = *(const short8*)(&As[(wr * 64 + mi * 16 + l16) * LDT + quad * 8]);
#pragma unroll
        for (int ni = 0; ni < 4; ni++)
            bfr[ni] = *(const short8*)(&Bs[(wc * 64 + ni * 16 + l16) * LDT + quad * 8]);
#pragma unroll
        for (int mi = 0; mi < 4; mi++)
#pragma unroll
            for (int ni = 0; ni < 4; ni++)
                acc[mi][ni] = __builtin_amdgcn_mfma_f32_16x16x32_bf16(af[mi], bfr[ni], acc[mi][ni], 0, 0, 0);
        __syncthreads();
    }

#pragma unroll
    for (int mi = 0; mi < 4; mi++) {
#pragma unroll
        for (int ni = 0; ni < 4; ni++) {
            int col = bn0 + wc * 64 + ni * 16 + l16;
#pragma unroll
            for (int r = 0; r < 4; r++) {
                int row = bm0 + wr * 64 + mi * 16 + quad * 4 + r;
                if (row < NN)
                    hb[(size_t)row * HC + col] = f2h(acc[mi][ni][r]);
            }
        }
    }
}

// ---------------- gather-aggregate v12: bucket CSR + v_perm/v_dot2_f32_f16 ----
// wave per node, half-wave edge interleave, 4 gather chains in flight.
// Bucket layout: node d's edges at rec[d*RCAP .. d*RCAP+cnt[d]).
// Tail zero-fill selector 0x0C (0x00 const class); 0x80 is 0xFF class -> NaN.
__global__ __launch_bounds__(256) void agg12_kernel(const unsigned short* __restrict__ hb,
                                                    const int* __restrict__ cnt,
                                                    const uint2* __restrict__ rec,
                                                    const float* __restrict__ bias,
                                                    unsigned short* __restrict__ aggb)
{
    int wave = threadIdx.x >> 6, lane = threadIdx.x & 63;
    int d = blockIdx.x * 4 + wave;
    int half = lane >> 5;
    int l = lane & 31;
    int c = l * 8;
    unsigned int selp  = (l & 16) ? 0x07060302u : 0x05040100u;
    unsigned int selps = (l & 16) ? 0x0C0C0302u : 0x0C0C0100u;   // (p, +0.0)
    const unsigned int ones = 0x3C003C00u;   // half2(1.0, 1.0)
    const unsigned long long* recq = (const unsigned long long*)rec;

    int j0 = d * RCAP;
    int j1 = j0 + cnt[d];
    float a0 = 0.f, a1 = 0.f, a2 = 0.f, a3 = 0.f;
    float a4 = 0.f, a5 = 0.f, a6 = 0.f, a7 = 0.f;
    float psum = 0.f;

    int j = j0 + half;
    for (; j + 6 < j1; j += 8) {
        unsigned long long q0 = recq[j], q1 = recq[j + 2], q2 = recq[j + 4], q3 = recq[j + 6];
        unsigned int pp01 = permb((unsigned int)(q1 >> 32), (unsigned int)(q0 >> 32), selp);
        unsigned int pp23 = permb((unsigned int)(q3 >> 32), (unsigned int)(q2 >> 32), selp);
        psum = fdot2u(pp01, ones, psum);
        psum = fdot2u(pp23, ones, psum);
        uint4 h0 = *(const uint4*)(hb + (size_t)(unsigned int)q0 * HC + c);
        uint4 h1 = *(const uint4*)(hb + (size_t)(unsigned int)q1 * HC + c);
        uint4 h2 = *(const uint4*)(hb + (size_t)(unsigned int)q2 * HC + c);
        uint4 h3 = *(const uint4*)(hb + (size_t)(unsigned int)q3 * HC + c);
        a0 = fdot2u(permb(h1.x, h0.x, 0x05040100u), pp01, a0);
        a0 = fdot2u(permb(h3.x, h2.x, 0x05040100u), pp23, a0);
        a1 = fdot2u(permb(h1.x, h0.x, 0x07060302u), pp01, a1);
        a1 = fdot2u(permb(h3.x, h2.x, 0x07060302u), pp23, a1);
        a2 = fdot2u(permb(h1.y, h0.y, 0x05040100u), pp01, a2);
        a2 = fdot2u(permb(h3.y, h2.y, 0x05040100u), pp23, a2);
        a3 = fdot2u(permb(h1.y, h0.y, 0x07060302u), pp01, a3);
        a3 = fdot2u(permb(h3.y, h2.y, 0x07060302u), pp23, a3);
        a4 = fdot2u(permb(h1.z, h0.z, 0x05040100u), pp01, a4);
        a4 = fdot2u(permb(h3.z, h2.z, 0x05040100u), pp23, a4);
        a5 = fdot2u(permb(h1.z, h0.z, 0x07060302u), pp01, a5);
        a5 = fdot2u(permb(h3.z, h2.z, 0x07060302u), pp23, a5);
        a6 = fdot2u(permb(h1.w, h0.w, 0x05040100u), pp01, a6);
        a6 = fdot2u(permb(h3.w, h2.w, 0x05040100u), pp23, a6);
        a7 = fdot2u(permb(h1.w, h0.w, 0x07060302u), pp01, a7);
        a7 = fdot2u(permb(h3.w, h2.w, 0x07060302u), pp23, a7);
    }
    for (; j < j1; j += 2) {
        unsigned long long q0 = recq[j];
        unsigned int pp = permb(0u, (unsigned int)(q0 >> 32), selps);
        psum = fdot2u(pp, ones, psum);
        uint4 h0 = *(const uint4*)(hb + (size_t)(unsigned int)q0 * HC + c);
        a0 = fdot2u(permb(0u, h0.x, 0x0C0C0100u), pp, a0);
        a1 = fdot2u(permb(0u, h0.x, 0x0C0C0302u), pp, a1);
        a2 = fdot2u(permb(0u, h0.y, 0x0C0C0100u), pp, a2);
        a3 = fdot2u(permb(0u, h0.y, 0x0C0C0302u), pp, a3);
        a4 = fdot2u(permb(0u, h0.z, 0x0C0C0100u), pp, a4);
        a5 = fdot2u(permb(0u, h0.z, 0x0C0C0302u), pp, a5);
        a6 = fdot2u(permb(0u, h0.w, 0x0C0C0100u), pp, a6);
        a7 = fdot2u(permb(0u, h0.w, 0x0C0C0302u), pp, a7);
    }

    a0 += __shfl_xor(a0, 32);
    a1 += __shfl_xor(a1, 32);
    a2 += __shfl_xor(a2, 32);
    a3 += __shfl_xor(a3, 32);
    a4 += __shfl_xor(a4, 32);
    a5 += __shfl_xor(a5, 32);
    a6 += __shfl_xor(a6, 32);
    a7 += __shfl_xor(a7, 32);
    psum += __shfl_xor(psum, 32);

    if (half == 0) {
        float inv = 1.f / fmaxf(psum, 1e-16f);
        float4 b0 = *(const float4*)(bias + c);
        float4 b1 = *(const float4*)(bias + c + 4);
        float v0 = a0 * inv + b0.x;
        float v1 = a1 * inv + b0.y;
        float v2 = a2 * inv + b0.z;
        float v3 = a3 * inv + b0.w;
        float v4 = a4 * inv + b1.x;
        float v5 = a5 * inv + b1.y;
        float v6 = a6 * inv + b1.z;
        float v7 = a7 * inv + b1.w;
        v0 = v0 > 0.f ? v0 : expm1f(v0);
        v1 = v1 > 0.f ? v1 : expm1f(v1);
        v2 = v2 > 0.f ? v2 : expm1f(v2);
        v3 = v3 > 0.f ? v3 : expm1f(v3);
        v4 = v4 > 0.f ? v4 : expm1f(v4);
        v5 = v5 > 0.f ? v5 : expm1f(v5);
        v6 = v6 > 0.f ? v6 : expm1f(v6);
        v7 = v7 > 0.f ? v7 : expm1f(v7);
        uint4 o;
        o.x = (unsigned int)f2bf(v0) | ((unsigned int)f2bf(v1) << 16);
        o.y = (unsigned int)f2bf(v2) | ((unsigned int)f2bf(v3) << 16);
        o.z = (unsigned int)f2bf(v4) | ((unsigned int)f2bf(v5) << 16);
        o.w = (unsigned int)f2bf(v6) | ((unsigned int)f2bf(v7) << 16);
        *(uint4*)(aggb + (size_t)d * HC + c) = o;
    }
}

// ---------------- launch ----------------
extern "C" void kernel_launch(void* const* d_in, const int* in_sizes, int n_in,
                              void* d_out, int out_size, void* d_ws, size_t ws_size,
                              hipStream_t stream)
{
    const float* x       = (const float*)d_in[0];
    const int*   ei32    = (const int*)d_in[1];
    const float* W       = (const float*)d_in[2];
    const float* att_src = (const float*)d_in[3];
    const float* att_dst = (const float*)d_in[4];
    const float* bias    = (const float*)d_in[5];
    const float* lin_w   = (const float*)d_in[6];
    const float* lin_b   = (const float*)d_in[7];
    float* out = (float*)d_out;

    char* ws = (char*)d_ws;
    size_t off = 0;
    auto alloc = [&](size_t bytes) -> void* {
        void* p = ws + off;
        off += (bytes + 255) & ~(size_t)255;
        return p;
    };

    // zero-init region first (cnt only)
    int*   cnt    = (int*)alloc((size_t)NN * 4);
    size_t zero_bytes = off;

    int*   flag     = (int*)alloc(256);
    float* was      = (float*)alloc((size_t)HH * FIN * 4);
    float* wad      = (float*)alloc((size_t)HH * FIN * 4);
    float* a_s      = (float*)alloc((size_t)NN * 2 * 4);
    float* a_d      = (float*)alloc((size_t)NN * 2 * 4);
    uint2* rec      = (uint2*)alloc((size_t)NN * RCAP * 8);   // 25.6 MB bucket array
    unsigned short* xb     = (unsigned short*)alloc((size_t)NN * FIN * 2);
    unsigned short* Wb     = (unsigned short*)alloc((size_t)HC * FIN * 2);
    unsigned short* linwb  = (unsigned short*)alloc((size_t)CCOUT * HC * 2);
    unsigned short* hb     = (unsigned short*)alloc((size_t)NN * HC * 2);   // fp16 [NN][HC]
    unsigned short* aggb   = (unsigned short*)alloc((size_t)NN * HC * 2);   // bf16 [NN][HC]

    hipMemsetAsync(d_ws, 0, zero_bytes, stream);

    prep_kernel<<<PREP_GRID, 256, 0, stream>>>(W, att_src, att_dst, lin_w, ei32,
                                               was, wad, Wb, linwb, flag);

    xprep_kernel<<<NB_XPREP, 256, 0, stream>>>(x, was, wad, xb, a_s, a_d);

    scatter_gemm1_kernel<<<NB_FUSE2, 256, 0, stream>>>(ei32, flag, cnt,
                                                       a_s, a_d, rec, xb, Wb, hb);

    agg12_kernel<<<NN / 4, 256, 0, stream>>>(hb, cnt, rec, bias, aggb);

    dim3 g2((NN + 127) / 128, CCOUT / 128);
    gemm_mfma<true, false><<<g2, 256, 0, stream>>>(aggb, linwb, lin_b, out, NN, CCOUT, HC);
}

// Round 9
// 257.262 us; speedup vs baseline: 1.1006x; 1.0042x over previous
//
#include <hip/hip_runtime.h>
#include <hip/hip_fp16.h>
#include <math.h>

#define NN 50000
#define EE 800000
#define ET (EE + NN)
#define FIN 256
#define CCOUT 128
#define HH 2
#define HC 256
#define NEG 0.2f
#define RCAP 64                          // slots per dst bucket; P(deg>=64) ~ 3e-17

#define NB_XPREP (NN / 4)

// prep grid: 1 detect + 2 watt + 64 W-conv + 32 linw-conv
#define PREP_W_BLOCKS 64
#define PREP_LW_BLOCKS 32
#define PREP_GRID (3 + PREP_W_BLOCKS + PREP_LW_BLOCKS)

// fused scatter+gemm1: scatter 4 edges/thread (831 blocks) 1:1-interleaved with
// 782 gemm blocks, then 49 scatter tail blocks.
#define G1X 391                          // (NN+127)/128
#define G1Y 2                            // HC/128
#define NB_G1 (G1X * G1Y)                // 782
#define NB_SCAT4 ((ET + 1023) / 1024)    // 831
#define PAIR_HEAD (2 * NB_G1)            // 1564
#define NB_FUSE2 (NB_SCAT4 + NB_G1)      // 1613

typedef __attribute__((ext_vector_type(8))) short short8;
typedef __attribute__((ext_vector_type(4))) float floatx4;
typedef _Float16 half2v __attribute__((ext_vector_type(2)));

// ---------------- helpers ----------------
__device__ __forceinline__ unsigned short f2bf(float f)
{
    union { float f; unsigned int u; } x; x.f = f;
    unsigned int r = x.u + 0x7fffu + ((x.u >> 16) & 1u);   // RNE
    return (unsigned short)(r >> 16);
}
__device__ __forceinline__ unsigned short f2h(float f)
{
    __half h = __float2half_rn(f);
    return *(const unsigned short*)&h;
}
__device__ __forceinline__ unsigned int permb(unsigned int a, unsigned int b, unsigned int s)
{
    return __builtin_amdgcn_perm(a, b, s);
}
__device__ __forceinline__ float fdot2u(unsigned int a, unsigned int b, float c)
{
    union { unsigned int u; half2v h; } x, y;
    x.u = a; y.u = b;
    return __builtin_amdgcn_fdot2(x.h, y.h, c, false);
}

__device__ __forceinline__ int load_idx(const int* ei32, int is64, int pos)
{
    return is64 ? ei32[2 * pos] : ei32[pos];
}

// ---------------- fused prep: detect + watt + weight bf16 conversion ----------------
__global__ __launch_bounds__(256) void prep_kernel(const float* __restrict__ W,
                                                   const float* __restrict__ att_s,
                                                   const float* __restrict__ att_d,
                                                   const float* __restrict__ lin_w,
                                                   const int* __restrict__ ei32,
                                                   float* __restrict__ was,
                                                   float* __restrict__ wad,
                                                   unsigned short* __restrict__ Wb,
                                                   unsigned short* __restrict__ linwb,
                                                   int* __restrict__ flag)
{
    int b = blockIdx.x, t = threadIdx.x;
    if (b == 0) {
        if (t < 64) {
            int v = ei32[2 * t + 1];
            unsigned long long m = __ballot(v != 0);
            if (t == 0) *flag = (m == 0ull) ? 1 : 0;
        }
    } else if (b <= 2) {
        int hd = b - 1;
        float as = 0.f, ad = 0.f;
        for (int c = 0; c < CCOUT; c++) {
            float wv = W[(size_t)(hd * CCOUT + c) * FIN + t];
            as += att_s[hd * CCOUT + c] * wv;
            ad += att_d[hd * CCOUT + c] * wv;
        }
        was[hd * FIN + t] = as;
        wad[hd * FIN + t] = ad;
    } else if (b < 3 + PREP_W_BLOCKS) {
        int i = (b - 3) * 256 + t;
        float4 v = *(const float4*)(W + (size_t)i * 4);
        ushort4 o;
        o.x = f2bf(v.x); o.y = f2bf(v.y); o.z = f2bf(v.z); o.w = f2bf(v.w);
        *(ushort4*)(Wb + (size_t)i * 4) = o;
    } else {
        int i = (b - 3 - PREP_W_BLOCKS) * 256 + t;
        float4 v = *(const float4*)(lin_w + (size_t)i * 4);
        ushort4 o;
        o.x = f2bf(v.x); o.y = f2bf(v.y); o.z = f2bf(v.z); o.w = f2bf(v.w);
        *(ushort4*)(linwb + (size_t)i * 4) = o;
    }
}

// ---------------- xprep: x->bf16 + fp32 attention logits (pure streaming) ----------------
__global__ __launch_bounds__(256) void xprep_kernel(const float* __restrict__ x,
                                                    const float* __restrict__ was,
                                                    const float* __restrict__ wad,
                                                    unsigned short* __restrict__ xb,
                                                    float* __restrict__ a_s,
                                                    float* __restrict__ a_d)
{
    int b = blockIdx.x, t = threadIdx.x;
    int w = t >> 6, l = t & 63;
    int n = b * 4 + w;
    float4 xv = *(const float4*)(x + (size_t)n * FIN + l * 4);
    ushort4 xs;
    xs.x = f2bf(xv.x); xs.y = f2bf(xv.y); xs.z = f2bf(xv.z); xs.w = f2bf(xv.w);
    *(ushort4*)(xb + (size_t)n * FIN + l * 4) = xs;

    float4 s0 = *(const float4*)(was + l * 4);
    float4 s1 = *(const float4*)(was + FIN + l * 4);
    float4 d0 = *(const float4*)(wad + l * 4);
    float4 d1 = *(const float4*)(wad + FIN + l * 4);
    float vs0 = xv.x * s0.x + xv.y * s0.y + xv.z * s0.z + xv.w * s0.w;
    float vs1 = xv.x * s1.x + xv.y * s1.y + xv.z * s1.z + xv.w * s1.w;
    float vd0 = xv.x * d0.x + xv.y * d0.y + xv.z * d0.z + xv.w * d0.w;
    float vd1 = xv.x * d1.x + xv.y * d1.y + xv.z * d1.z + xv.w * d1.w;
#pragma unroll
    for (int off = 32; off > 0; off >>= 1) {
        vs0 += __shfl_down(vs0, off);
        vs1 += __shfl_down(vs1, off);
        vd0 += __shfl_down(vd0, off);
        vd1 += __shfl_down(vd1, off);
    }
    if (l == 0) {
        a_s[n * 2 + 0] = vs0; a_s[n * 2 + 1] = vs1;
        a_d[n * 2 + 0] = vd0; a_d[n * 2 + 1] = vd1;
    }
}

// ---------------- MFMA bf16 GEMM (standalone, used for GEMM2) ----------------
template <bool ADD_BIAS, bool OUT_BF16>
__global__ __launch_bounds__(256) void gemm_mfma(const unsigned short* __restrict__ A,
                                                 const unsigned short* __restrict__ B,
                                                 const float* __restrict__ bias,
                                                 void* __restrict__ Cout,
                                                 int M, int N, int K)
{
    const int LDT = 40;
    __shared__ unsigned short As[128 * LDT];
    __shared__ unsigned short Bs[128 * LDT];

    int tid = threadIdx.x;
    int wave = tid >> 6, lane = tid & 63;
    int wr = wave >> 1, wc = wave & 1;
    int quad = lane >> 4, l16 = lane & 15;
    int bm0 = blockIdx.x * 128;
    int bn0 = blockIdx.y * 128;

    floatx4 acc[4][4] = {};

    for (int kk = 0; kk < K; kk += 32) {
#pragma unroll
        for (int p = 0; p < 2; p++) {
            int idx = p * 256 + tid;
            int row = idx >> 2, seg = idx & 3;
            int grow = bm0 + row; if (grow >= M) grow = M - 1;
            uint4 va = *(const uint4*)(A + (size_t)grow * K + kk + seg * 8);
            *(uint4*)(&As[row * LDT + seg * 8]) = va;
            uint4 vb = *(const uint4*)(B + (size_t)(bn0 + row) * K + kk + seg * 8);
            *(uint4*)(&Bs[row * LDT + seg * 8]) = vb;
        }
        __syncthreads();

        short8 af[4], bfr[4];
#pragma unroll
        for (int mi = 0; mi < 4; mi++)
            af[mi] = *(const short8*)(&As[(wr * 64 + mi * 16 + l16) * LDT + quad * 8]);
#pragma unroll
        for (int ni = 0; ni < 4; ni++)
            bfr[ni] = *(const short8*)(&Bs[(wc * 64 + ni * 16 + l16) * LDT + quad * 8]);
#pragma unroll
        for (int mi = 0; mi < 4; mi++)
#pragma unroll
            for (int ni = 0; ni < 4; ni++)
                acc[mi][ni] = __builtin_amdgcn_mfma_f32_16x16x32_bf16(af[mi], bfr[ni], acc[mi][ni], 0, 0, 0);
        __syncthreads();
    }

#pragma unroll
    for (int mi = 0; mi < 4; mi++) {
#pragma unroll
        for (int ni = 0; ni < 4; ni++) {
            int col = bn0 + wc * 64 + ni * 16 + l16;
#pragma unroll
            for (int r = 0; r < 4; r++) {
                int row = bm0 + wr * 64 + mi * 16 + quad * 4 + r;
                if (row < M) {
                    float v = acc[mi][ni][r];
                    if (ADD_BIAS) v += bias[col];
                    if (OUT_BF16)
                        ((unsigned short*)Cout)[(size_t)row * N + col] = f2bf(v);
                    else
                        ((float*)Cout)[(size_t)row * N + col] = v;
                }
            }
        }
    }
}

// ---------------- FUSED: scatter (rank-atomic, 4 edges/thread) + GEMM1, 1:1 ----
// R9: cnt counters padded to ONE PER 64B LINE (cnt[d*16]). Packed ints had 16
// counters/line -> 272 serialized same-line RMWs; padding cuts it to 17 (the
// true per-address contention). Line-granular atomic serialization at the
// coherence point was the ~50-65us wall seen in R4-R8.
__global__ __launch_bounds__(256) void scatter_gemm1_kernel(
        const int* __restrict__ ei32, const int* __restrict__ flag,
        int* __restrict__ cnt,
        const float* __restrict__ a_s, const float* __restrict__ a_d,
        uint2* __restrict__ rec,
        const unsigned short* __restrict__ A,   // xb [NN, FIN]
        const unsigned short* __restrict__ B,   // Wb [HC, FIN]
        unsigned short* __restrict__ hb)        // out [NN, HC] fp16
{
    const int LDT = 40;
    __shared__ unsigned short As[128 * LDT];
    __shared__ unsigned short Bs[128 * LDT];

    int b = blockIdx.x, tid = threadIdx.x;
    int sb = -1, gb = -1;
    if (b < PAIR_HEAD) {
        if (b & 1) sb = b >> 1; else gb = b >> 1;
    } else {
        sb = NB_G1 + (b - PAIR_HEAD);
    }

    if (sb >= 0) {
        int base = sb * 1024 + tid;
        int is64 = *flag;
        int ss[4], dd[4];
#pragma unroll
        for (int k = 0; k < 4; k++) {
            int e = base + k * 256;
            ss[k] = -1; dd[k] = 0;
            if (e < ET) {
                if (e < EE) { ss[k] = load_idx(ei32, is64, e); dd[k] = load_idx(ei32, is64, EE + e); }
                else { ss[k] = dd[k] = e - EE; }
            }
        }
        int rk[4];
#pragma unroll
        for (int k = 0; k < 4; k++)
            rk[k] = (ss[k] >= 0) ? atomicAdd(&cnt[dd[k] << 4], 1) : 0;
#pragma unroll
        for (int k = 0; k < 4; k++) {
            if (ss[k] < 0) continue;
            float e0 = a_s[ss[k] * 2 + 0] + a_d[dd[k] * 2 + 0];
            float e1 = a_s[ss[k] * 2 + 1] + a_d[dd[k] * 2 + 1];
            e0 = e0 > 0.f ? e0 : NEG * e0;
            e1 = e1 > 0.f ? e1 : NEG * e1;
            __half2 hp = __floats2half2_rn(__expf(e0), __expf(e1));
            uint2 r;
            r.x = (unsigned int)ss[k];
            r.y = *(unsigned int*)&hp;
            if (rk[k] < RCAP)
                rec[(size_t)dd[k] * RCAP + rk[k]] = r;
        }
        return;
    }

    int bx = gb % G1X, by = gb / G1X;
    int wave = tid >> 6, lane = tid & 63;
    int wr = wave >> 1, wc = wave & 1;
    int quad = lane >> 4, l16 = lane & 15;
    int bm0 = bx * 128;
    int bn0 = by * 128;

    floatx4 acc[4][4] = {};

    for (int kk = 0; kk < FIN; kk += 32) {
#pragma unroll
        for (int p = 0; p < 2; p++) {
            int idx = p * 256 + tid;
            int row = idx >> 2, seg = idx & 3;
            int grow = bm0 + row; if (grow >= NN) grow = NN - 1;
            uint4 va = *(const uint4*)(A + (size_t)grow * FIN + kk + seg * 8);
            *(uint4*)(&As[row * LDT + seg * 8]) = va;
            uint4 vb = *(const uint4*)(B + (size_t)(bn0 + row) * FIN + kk + seg * 8);
            *(uint4*)(&Bs[row * LDT + seg * 8]) = vb;
        }
        __syncthreads();

        short8 af[4], bfr[4];
#pragma unroll
        for (int mi = 0; mi < 4; mi++)
            af[mi] = *(const short8*)(&As[(wr * 64 + mi * 16 + l16) * LDT + quad * 8]);
#pragma unroll
        for (int ni = 0; ni < 4; ni++)
            bfr[ni] = *(const short8*)(&Bs[(wc * 64 + ni * 16 + l16) * LDT + quad * 8]);
#pragma unroll
        for (int mi = 0; mi < 4; mi++)
#pragma unroll
            for (int ni = 0; ni < 4; ni++)
                acc[mi][ni] = __builtin_amdgcn_mfma_f32_16x16x32_bf16(af[mi], bfr[ni], acc[mi][ni], 0, 0, 0);
        __syncthreads();
    }

#pragma unroll
    for (int mi = 0; mi < 4; mi++) {
#pragma unroll
        for (int ni = 0; ni < 4; ni++) {
            int col = bn0 + wc * 64 + ni * 16 + l16;
#pragma unroll
            for (int r = 0; r < 4; r++) {
                int row = bm0 + wr * 64 + mi * 16 + quad * 4 + r;
                if (row < NN)
                    hb[(size_t)row * HC + col] = f2h(acc[mi][ni][r]);
            }
        }
    }
}

// ---------------- gather-aggregate v12: bucket CSR + v_perm/v_dot2_f32_f16 ----
// wave per node, half-wave edge interleave, 4 gather chains in flight.
// Bucket layout: node d's edges at rec[d*RCAP .. d*RCAP+cnt[d*16]).
// Tail zero-fill selector 0x0C (0x00 const class); 0x80 is 0xFF class -> NaN.
__global__ __launch_bounds__(256) void agg12_kernel(const unsigned short* __restrict__ hb,
                                                    const int* __restrict__ cnt,
                                                    const uint2* __restrict__ rec,
                                                    const float* __restrict__ bias,
                                                    unsigned short* __restrict__ aggb)
{
    int wave = threadIdx.x >> 6, lane = threadIdx.x & 63;
    int d = blockIdx.x * 4 + wave;
    int half = lane >> 5;
    int l = lane & 31;
    int c = l * 8;
    unsigned int selp  = (l & 16) ? 0x07060302u : 0x05040100u;
    unsigned int selps = (l & 16) ? 0x0C0C0302u : 0x0C0C0100u;   // (p, +0.0)
    const unsigned int ones = 0x3C003C00u;   // half2(1.0, 1.0)
    const unsigned long long* recq = (const unsigned long long*)rec;

    int j0 = d * RCAP;
    int j1 = j0 + cnt[d << 4];
    float a0 = 0.f, a1 = 0.f, a2 = 0.f, a3 = 0.f;
    float a4 = 0.f, a5 = 0.f, a6 = 0.f, a7 = 0.f;
    float psum = 0.f;

    int j = j0 + half;
    for (; j + 6 < j1; j += 8) {
        unsigned long long q0 = recq[j], q1 = recq[j + 2], q2 = recq[j + 4], q3 = recq[j + 6];
        unsigned int pp01 = permb((unsigned int)(q1 >> 32), (unsigned int)(q0 >> 32), selp);
        unsigned int pp23 = permb((unsigned int)(q3 >> 32), (unsigned int)(q2 >> 32), selp);
        psum = fdot2u(pp01, ones, psum);
        psum = fdot2u(pp23, ones, psum);
        uint4 h0 = *(const uint4*)(hb + (size_t)(unsigned int)q0 * HC + c);
        uint4 h1 = *(const uint4*)(hb + (size_t)(unsigned int)q1 * HC + c);
        uint4 h2 = *(const uint4*)(hb + (size_t)(unsigned int)q2 * HC + c);
        uint4 h3 = *(const uint4*)(hb + (size_t)(unsigned int)q3 * HC + c);
        a0 = fdot2u(permb(h1.x, h0.x, 0x05040100u), pp01, a0);
        a0 = fdot2u(permb(h3.x, h2.x, 0x05040100u), pp23, a0);
        a1 = fdot2u(permb(h1.x, h0.x, 0x07060302u), pp01, a1);
        a1 = fdot2u(permb(h3.x, h2.x, 0x07060302u), pp23, a1);
        a2 = fdot2u(permb(h1.y, h0.y, 0x05040100u), pp01, a2);
        a2 = fdot2u(permb(h3.y, h2.y, 0x05040100u), pp23, a2);
        a3 = fdot2u(permb(h1.y, h0.y, 0x07060302u), pp01, a3);
        a3 = fdot2u(permb(h3.y, h2.y, 0x07060302u), pp23, a3);
        a4 = fdot2u(permb(h1.z, h0.z, 0x05040100u), pp01, a4);
        a4 = fdot2u(permb(h3.z, h2.z, 0x05040100u), pp23, a4);
        a5 = fdot2u(permb(h1.z, h0.z, 0x07060302u), pp01, a5);
        a5 = fdot2u(permb(h3.z, h2.z, 0x07060302u), pp23, a5);
        a6 = fdot2u(permb(h1.w, h0.w, 0x05040100u), pp01, a6);
        a6 = fdot2u(permb(h3.w, h2.w, 0x05040100u), pp23, a6);
        a7 = fdot2u(permb(h1.w, h0.w, 0x07060302u), pp01, a7);
        a7 = fdot2u(permb(h3.w, h2.w, 0x07060302u), pp23, a7);
    }
    for (; j < j1; j += 2) {
        unsigned long long q0 = recq[j];
        unsigned int pp = permb(0u, (unsigned int)(q0 >> 32), selps);
        psum = fdot2u(pp, ones, psum);
        uint4 h0 = *(const uint4*)(hb + (size_t)(unsigned int)q0 * HC + c);
        a0 = fdot2u(permb(0u, h0.x, 0x0C0C0100u), pp, a0);
        a1 = fdot2u(permb(0u, h0.x, 0x0C0C0302u), pp, a1);
        a2 = fdot2u(permb(0u, h0.y, 0x0C0C0100u), pp, a2);
        a3 = fdot2u(permb(0u, h0.y, 0x0C0C0302u), pp, a3);
        a4 = fdot2u(permb(0u, h0.z, 0x0C0C0100u), pp, a4);
        a5 = fdot2u(permb(0u, h0.z, 0x0C0C0302u), pp, a5);
        a6 = fdot2u(permb(0u, h0.w, 0x0C0C0100u), pp, a6);
        a7 = fdot2u(permb(0u, h0.w, 0x0C0C0302u), pp, a7);
    }

    a0 += __shfl_xor(a0, 32);
    a1 += __shfl_xor(a1, 32);
    a2 += __shfl_xor(a2, 32);
    a3 += __shfl_xor(a3, 32);
    a4 += __shfl_xor(a4, 32);
    a5 += __shfl_xor(a5, 32);
    a6 += __shfl_xor(a6, 32);
    a7 += __shfl_xor(a7, 32);
    psum += __shfl_xor(psum, 32);

    if (half == 0) {
        float inv = 1.f / fmaxf(psum, 1e-16f);
        float4 b0 = *(const float4*)(bias + c);
        float4 b1 = *(const float4*)(bias + c + 4);
        float v0 = a0 * inv + b0.x;
        float v1 = a1 * inv + b0.y;
        float v2 = a2 * inv + b0.z;
        float v3 = a3 * inv + b0.w;
        float v4 = a4 * inv + b1.x;
        float v5 = a5 * inv + b1.y;
        float v6 = a6 * inv + b1.z;
        float v7 = a7 * inv + b1.w;
        v0 = v0 > 0.f ? v0 : expm1f(v0);
        v1 = v1 > 0.f ? v1 : expm1f(v1);
        v2 = v2 > 0.f ? v2 : expm1f(v2);
        v3 = v3 > 0.f ? v3 : expm1f(v3);
        v4 = v4 > 0.f ? v4 : expm1f(v4);
        v5 = v5 > 0.f ? v5 : expm1f(v5);
        v6 = v6 > 0.f ? v6 : expm1f(v6);
        v7 = v7 > 0.f ? v7 : expm1f(v7);
        uint4 o;
        o.x = (unsigned int)f2bf(v0) | ((unsigned int)f2bf(v1) << 16);
        o.y = (unsigned int)f2bf(v2) | ((unsigned int)f2bf(v3) << 16);
        o.z = (unsigned int)f2bf(v4) | ((unsigned int)f2bf(v5) << 16);
        o.w = (unsigned int)f2bf(v6) | ((unsigned int)f2bf(v7) << 16);
        *(uint4*)(aggb + (size_t)d * HC + c) = o;
    }
}

// ---------------- launch ----------------
extern "C" void kernel_launch(void* const* d_in, const int* in_sizes, int n_in,
                              void* d_out, int out_size, void* d_ws, size_t ws_size,
                              hipStream_t stream)
{
    const float* x       = (const float*)d_in[0];
    const int*   ei32    = (const int*)d_in[1];
    const float* W       = (const float*)d_in[2];
    const float* att_src = (const float*)d_in[3];
    const float* att_dst = (const float*)d_in[4];
    const float* bias    = (const float*)d_in[5];
    const float* lin_w   = (const float*)d_in[6];
    const float* lin_b   = (const float*)d_in[7];
    float* out = (float*)d_out;

    char* ws = (char*)d_ws;
    size_t off = 0;
    auto alloc = [&](size_t bytes) -> void* {
        void* p = ws + off;
        off += (bytes + 255) & ~(size_t)255;
        return p;
    };

    // zero-init region first (cnt only; one counter per 64B line -> 3.2MB)
    int*   cnt    = (int*)alloc((size_t)NN * 64);
    size_t zero_bytes = off;

    int*   flag     = (int*)alloc(256);
    float* was      = (float*)alloc((size_t)HH * FIN * 4);
    float* wad      = (float*)alloc((size_t)HH * FIN * 4);
    float* a_s      = (float*)alloc((size_t)NN * 2 * 4);
    float* a_d      = (float*)alloc((size_t)NN * 2 * 4);
    uint2* rec      = (uint2*)alloc((size_t)NN * RCAP * 8);   // 25.6 MB bucket array
    unsigned short* xb     = (unsigned short*)alloc((size_t)NN * FIN * 2);
    unsigned short* Wb     = (unsigned short*)alloc((size_t)HC * FIN * 2);
    unsigned short* linwb  = (unsigned short*)alloc((size_t)CCOUT * HC * 2);
    unsigned short* hb     = (unsigned short*)alloc((size_t)NN * HC * 2);   // fp16 [NN][HC]
    unsigned short* aggb   = (unsigned short*)alloc((size_t)NN * HC * 2);   // bf16 [NN][HC]

    hipMemsetAsync(d_ws, 0, zero_bytes, stream);

    prep_kernel<<<PREP_GRID, 256, 0, stream>>>(W, att_src, att_dst, lin_w, ei32,
                                               was, wad, Wb, linwb, flag);

    xprep_kernel<<<NB_XPREP, 256, 0, stream>>>(x, was, wad, xb, a_s, a_d);

    scatter_gemm1_kernel<<<NB_FUSE2, 256, 0, stream>>>(ei32, flag, cnt,
                                                       a_s, a_d, rec, xb, Wb, hb);

    agg12_kernel<<<NN / 4, 256, 0, stream>>>(hb, cnt, rec, bias, aggb);

    dim3 g2((NN + 127) / 128, CCOUT / 128);
    gemm_mfma<true, false><<<g2, 256, 0, stream>>>(aggb, linwb, lin_b, out, NN, CCOUT, HC);
}